// Round 1
// baseline (878.084 us; speedup 1.0000x reference)
//
#include <hip/hip_runtime.h>
#include <math.h>

#define NB 8
#define NC 96
#define NH 128
#define NWID 128
#define NN (NH*NWID)      // 16384
#define NCO 192
#define NM (NC*NN)        // 1572864

// workspace layout (float offsets)
#define WS_SUMS   0                     // [2][8][2]  (zeroed)
#define WS_SC     32                    // [8][32][32] (zeroed)
#define WS_AC     8224                  // [8][32][32]
#define WS_SU     16416                 // [8][96]
#define WS_TU     17184
#define WS_SD     17952
#define WS_TD     18720
#define WS_RU     19488                 // resc_u [8][96]
#define WS_RD     20256                 // resc_d
#define WS_CADD   21024                 // rebias_u+rebias_d
#define WS_BPU    21792                 // eff bias [8][192]
#define WS_BPD    23328
#define WS_WPU    24864                 // eff W transposed [8][96][192]
#define WS_WPD    172320
#define WS_QKVU   327680                // [8][192][16384]
#define WS_QKVD   (WS_QKVU + NB*NCO*NN)

// ---------------- stats reduction: per-sample sum & sumsq ----------------
__global__ __launch_bounds__(256) void reduce_stats(const float* __restrict__ xu,
                                                    const float* __restrict__ xd,
                                                    float* __restrict__ ws) {
  int blk = blockIdx.x;                // 2*8*64
  int tensor = blk >> 9;
  int b = (blk >> 6) & 7;
  int chunk = blk & 63;
  const float* x = tensor ? xd : xu;
  const float4* p = (const float4*)(x + (size_t)b*NM + (size_t)chunk*(NM/64));
  float s = 0.f, sq = 0.f;
  for (int r = 0; r < 24; r++) {
    float4 v = p[threadIdx.x + r*256];
    s  += v.x + v.y + v.z + v.w;
    sq += v.x*v.x + v.y*v.y + v.z*v.z + v.w*v.w;
  }
  for (int o = 32; o; o >>= 1) { s += __shfl_down(s, o); sq += __shfl_down(sq, o); }
  __shared__ float ls[8];
  int wv = threadIdx.x >> 6, ln = threadIdx.x & 63;
  if (ln == 0) { ls[wv*2] = s; ls[wv*2+1] = sq; }
  __syncthreads();
  if (threadIdx.x == 0) {
    s  = ls[0] + ls[2] + ls[4] + ls[6];
    sq = ls[1] + ls[3] + ls[5] + ls[7];
    atomicAdd(&ws[WS_SUMS + (tensor*8 + b)*2],     s);
    atomicAdd(&ws[WS_SUMS + (tensor*8 + b)*2 + 1], sq);
  }
}

// ---------------- derived params: LN folded into GEMM weight/bias ----------------
__global__ void compute_params(float* __restrict__ ws,
    const float* __restrict__ nwu, const float* __restrict__ nbu,
    const float* __restrict__ m1wu, const float* __restrict__ m1bu,
    const float* __restrict__ m2wu, const float* __restrict__ m2bu,
    const float* __restrict__ nwd, const float* __restrict__ nbd,
    const float* __restrict__ m1wd, const float* __restrict__ m1bd,
    const float* __restrict__ m2wd, const float* __restrict__ m2bd,
    const float* __restrict__ Wqu, const float* __restrict__ bqu,
    const float* __restrict__ Wqd, const float* __restrict__ bqd) {
  __shared__ float meanL[16], stdL[16];
  __shared__ float tuL[768], tdL[768];
  int t = threadIdx.x;
  if (t < 16) {
    float s = ws[WS_SUMS + t*2], sq = ws[WS_SUMS + t*2 + 1];
    const float inv = 1.f / (float)NM;
    float mean = s * inv;
    float var  = sq * inv - mean*mean;
    meanL[t] = mean;
    stdL[t]  = sqrtf(var + 1e-5f);
  }
  __syncthreads();
  for (int idx = t; idx < 768; idx += 256) {
    int b = idx / 96, c = idx % 96;
    float mu = meanL[b],   su = stdL[b];
    float md = meanL[8+b], sd = stdL[8+b];
    float scu = nwu[c] / su;
    float scd = nwd[c] / sd;
    float tcu = nbu[c] - mu*scu;
    float tcd = nbd[c] - md*scd;
    tuL[idx] = tcu; tdL[idx] = tcd;
    ws[WS_SU+idx] = scu; ws[WS_TU+idx] = tcu;
    ws[WS_SD+idx] = scd; ws[WS_TD+idx] = tcd;
    ws[WS_RU+idx] = su*m1wu[c] + m1bu[c];
    ws[WS_RD+idx] = sd*m1wd[c] + m1bd[c];
    ws[WS_CADD+idx] = (mu*m2wu[c] + m2bu[c]) + (md*m2wd[c] + m2bd[c]);
  }
  __syncthreads();
  for (int idx = t; idx < 3072; idx += 256) {
    int tensor = idx / 1536;
    int r = idx % 1536;
    int b = r / 192, o = r % 192;
    const float* Wq = tensor ? Wqd : Wqu;
    const float* tt = tensor ? tdL : tuL;
    float acc = tensor ? bqd[o] : bqu[o];
    for (int i = 0; i < 96; i++) acc += Wq[o*96 + i] * tt[b*96 + i];
    ws[(tensor ? WS_BPD : WS_BPU) + r] = acc;
  }
}

// ---------------- W' = W * scale, stored transposed [b][i][o] ----------------
__global__ __launch_bounds__(256) void compute_wprime(float* __restrict__ ws,
    const float* __restrict__ Wqu, const float* __restrict__ Wqd) {
  int idx = blockIdx.x*256 + threadIdx.x;   // 294912 total
  int tensor = idx / 147456;
  int r = idx % 147456;
  int b  = r / 18432;
  int r2 = r % 18432;
  int i  = r2 / 192, o = r2 % 192;
  const float* Wq = tensor ? Wqd : Wqu;
  const float* s  = ws + (tensor ? WS_SD : WS_SU);
  ws[(tensor ? WS_WPD : WS_WPU) + r] = Wq[o*96 + i] * s[b*96 + i];
}

// ---------------- qkv GEMM: [192 x 16384] = W'[192x96] @ x[96x16384] ----------------
__global__ __launch_bounds__(256) void qkv_gemm(float* __restrict__ ws,
    const float* __restrict__ xu, const float* __restrict__ xd) {
  __shared__ float xs[96][128];     // 48 KB
  __shared__ float wst[96][192];    // 72 KB, [i][o]
  int blk = blockIdx.x;             // 2*8*128
  int tensor = blk >> 10;
  int rem = blk & 1023;
  int b = rem >> 7;
  int nt = rem & 127;
  const float* x  = tensor ? xd : xu;
  const float* wp = ws + (tensor ? WS_WPD : WS_WPU) + (size_t)b*18432;
  const float* bp = ws + (tensor ? WS_BPD : WS_BPU) + b*192;
  float* outq = ws + (tensor ? WS_QKVD : WS_QKVU) + (size_t)b*NCO*NN;
  int t = threadIdx.x;
  for (int r = 0; r < 12; r++) {                       // x tile 96x128
    int idx = t + r*256;
    int i = idx >> 5, c4 = idx & 31;
    *(float4*)&xs[i][c4*4] = *(const float4*)(x + (size_t)b*NM + (size_t)i*NN + nt*128 + c4*4);
  }
  {
    const float4* wsrc = (const float4*)wp;            // 4608 float4
    float4* wdst = (float4*)&wst[0][0];
    for (int r = 0; r < 18; r++) wdst[t + r*256] = wsrc[t + r*256];
  }
  __syncthreads();
  int n4 = t & 31, og = t >> 5;                        // o base = og*24, n base = n4*4
  float4 acc[24];
  #pragma unroll
  for (int k = 0; k < 24; k++) acc[k] = make_float4(0.f,0.f,0.f,0.f);
  for (int i = 0; i < 96; i++) {
    float4 xv = *(const float4*)&xs[i][n4*4];
    const float* wrow = &wst[i][og*24];
    #pragma unroll
    for (int k6 = 0; k6 < 6; k6++) {
      float4 wv = *(const float4*)&wrow[k6*4];
      acc[k6*4+0].x += wv.x*xv.x; acc[k6*4+0].y += wv.x*xv.y; acc[k6*4+0].z += wv.x*xv.z; acc[k6*4+0].w += wv.x*xv.w;
      acc[k6*4+1].x += wv.y*xv.x; acc[k6*4+1].y += wv.y*xv.y; acc[k6*4+1].z += wv.y*xv.z; acc[k6*4+1].w += wv.y*xv.w;
      acc[k6*4+2].x += wv.z*xv.x; acc[k6*4+2].y += wv.z*xv.y; acc[k6*4+2].z += wv.z*xv.z; acc[k6*4+2].w += wv.z*xv.w;
      acc[k6*4+3].x += wv.w*xv.x; acc[k6*4+3].y += wv.w*xv.y; acc[k6*4+3].z += wv.w*xv.z; acc[k6*4+3].w += wv.w*xv.w;
    }
  }
  #pragma unroll
  for (int ko = 0; ko < 24; ko++) {
    int o = og*24 + ko;
    float bb = bp[o];
    float4 v = acc[ko];
    v.x += bb; v.y += bb; v.z += bb; v.w += bb;
    *(float4*)(outq + (size_t)o*NN + nt*128 + n4*4) = v;
  }
}

// ---------------- height-axis attention (out channels 0..31) ----------------
__global__ __launch_bounds__(256) void attn_h(float* __restrict__ ws,
    const float* __restrict__ xu, const float* __restrict__ xd,
    float* __restrict__ out, const float* __restrict__ scale_p) {
  __shared__ float Qs[32][132], Ks[32][132], Vds[32][132], Vus[32][132];
  __shared__ float Ss[128][132];
  int b = blockIdx.x >> 7, w = blockIdx.x & 127;
  int t = threadIdx.x;
  const float* qkvu = ws + WS_QKVU + (size_t)b*NCO*NN;
  const float* qkvd = ws + WS_QKVD + (size_t)b*NCO*NN;
  for (int r = 0; r < 16; r++) {
    int idx = t + r*256; int c = idx >> 7, h = idx & 127;
    size_t o1 = (size_t)c*NN + (size_t)h*NWID + w;
    size_t o2 = (size_t)(96+c)*NN + (size_t)h*NWID + w;
    Qs[c][h]  = qkvu[o1];
    Ks[c][h]  = qkvd[o1];
    Vus[c][h] = qkvu[o2];
    Vds[c][h] = qkvd[o2];
  }
  __syncthreads();
  float sc = scale_p[0];
  int j = t & 127, ib = (t >> 7) * 64;
  for (int g = 0; g < 16; g++) {
    int i0 = ib + g*4;
    float a0=0.f, a1=0.f, a2=0.f, a3=0.f;
    for (int c = 0; c < 32; c++) {
      float kv = Ks[c][j];
      float4 q = *(const float4*)&Qs[c][i0];
      a0 += q.x*kv; a1 += q.y*kv; a2 += q.z*kv; a3 += q.w*kv;
    }
    Ss[i0+0][j] = a0*sc; Ss[i0+1][j] = a1*sc; Ss[i0+2][j] = a2*sc; Ss[i0+3][j] = a3*sc;
  }
  __syncthreads();
  {
    int wv = t >> 6, ln = t & 63;
    for (int r = 0; r < 32; r++) {
      int i = wv*32 + r;
      float s0 = Ss[i][ln], s1 = Ss[i][ln+64];
      float m = fmaxf(s0, s1);
      #pragma unroll
      for (int off = 32; off; off >>= 1) m = fmaxf(m, __shfl_xor(m, off));
      float e0 = __expf(s0 - m), e1 = __expf(s1 - m);
      float sum = e0 + e1;
      #pragma unroll
      for (int off = 32; off; off >>= 1) sum += __shfl_xor(sum, off);
      float inv = 1.f / sum;
      Ss[i][ln] = e0*inv; Ss[i][ln+64] = e1*inv;
    }
  }
  __syncthreads();
  int h = t & 127, ch0 = t >> 7;
  float accd[16], accu[16];
  #pragma unroll
  for (int r = 0; r < 16; r++) { accd[r]=0.f; accu[r]=0.f; }
  for (int j4 = 0; j4 < 32; j4++) {
    float4 sv = *(const float4*)&Ss[h][j4*4];
    #pragma unroll
    for (int r = 0; r < 16; r++) {
      float4 vv = *(const float4*)&Vds[ch0 + 2*r][j4*4];
      accd[r] += sv.x*vv.x + sv.y*vv.y + sv.z*vv.z + sv.w*vv.w;
    }
  }
  for (int i4 = 0; i4 < 32; i4++) {
    float p0 = Ss[i4*4+0][h], p1 = Ss[i4*4+1][h], p2 = Ss[i4*4+2][h], p3 = Ss[i4*4+3][h];
    #pragma unroll
    for (int r = 0; r < 16; r++) {
      float4 vv = *(const float4*)&Vus[ch0 + 2*r][i4*4];
      accu[r] += p0*vv.x + p1*vv.y + p2*vv.z + p3*vv.w;
    }
  }
  #pragma unroll
  for (int r = 0; r < 16; r++) {
    int c = ch0 + 2*r;
    float ruv = ws[WS_RU + b*96 + c];
    float rdv = ws[WS_RD + b*96 + c];
    float cav = ws[WS_CADD + b*96 + c];
    size_t off = ((size_t)(b*NC + c)*NH + h)*NWID + w;
    out[off] = accd[r]*ruv + accu[r]*rdv + cav + xu[off] + xd[off];
  }
}

// ---------------- width-axis attention (out channels 32..63) ----------------
__global__ __launch_bounds__(256) void attn_w(float* __restrict__ ws,
    const float* __restrict__ xu, const float* __restrict__ xd,
    float* __restrict__ out, const float* __restrict__ scale_p) {
  __shared__ float Qs[32][132], Ks[32][132], Vds[32][132], Vus[32][132];
  __shared__ float Ss[128][132];
  __shared__ float m1[128], l1[128], m2[128], l2[128];
  int b = blockIdx.x >> 7, hrow = blockIdx.x & 127;
  int t = threadIdx.x;
  const float* qkvu = ws + WS_QKVU + (size_t)b*NCO*NN;
  const float* qkvd = ws + WS_QKVD + (size_t)b*NCO*NN;
  size_t rowoff = (size_t)hrow * NWID;
  for (int r = 0; r < 16; r++) {
    int idx = t + r*256; int c = idx >> 7, wv_ = idx & 127;
    Qs[c][wv_]  = qkvu[(size_t)(32+c)*NN + rowoff + wv_];
    Ks[c][wv_]  = qkvd[(size_t)(32+c)*NN + rowoff + wv_];
    Vus[c][wv_] = qkvu[(size_t)(128+c)*NN + rowoff + wv_];
    Vds[c][wv_] = qkvd[(size_t)(128+c)*NN + rowoff + wv_];
  }
  __syncthreads();
  float sc = scale_p[0];
  int j = t & 127, ib = (t >> 7) * 64;
  for (int g = 0; g < 16; g++) {
    int i0 = ib + g*4;
    float a0=0.f, a1=0.f, a2=0.f, a3=0.f;
    for (int c = 0; c < 32; c++) {
      float kv = Ks[c][j];
      float4 q = *(const float4*)&Qs[c][i0];
      a0 += q.x*kv; a1 += q.y*kv; a2 += q.z*kv; a3 += q.w*kv;
    }
    Ss[i0+0][j] = a0*sc; Ss[i0+1][j] = a1*sc; Ss[i0+2][j] = a2*sc; Ss[i0+3][j] = a3*sc;
  }
  __syncthreads();
  {
    int wv = t >> 6, ln = t & 63;
    for (int r = 0; r < 32; r++) {
      int i = wv*32 + r;
      float s0 = Ss[i][ln], s1 = Ss[i][ln+64];
      float m = fmaxf(s0, s1);
      #pragma unroll
      for (int off = 32; off; off >>= 1) m = fmaxf(m, __shfl_xor(m, off));
      float e0 = __expf(s0 - m), e1 = __expf(s1 - m);
      float sum = e0 + e1;
      #pragma unroll
      for (int off = 32; off; off >>= 1) sum += __shfl_xor(sum, off);
      if (ln == 0) { m1[i] = m; l1[i] = sum; }
    }
  }
  if (t < 128) {
    float m = -3.0e38f;
    for (int i = 0; i < 128; i++) m = fmaxf(m, Ss[i][t]);
    float s = 0.f;
    for (int i = 0; i < 128; i++) s += __expf(Ss[i][t] - m);
    m2[t] = m; l2[t] = s;
  }
  __syncthreads();
  {
    int i0 = t >> 7;
    for (int r = 0; r < 64; r++) {
      int i = i0 + 2*r;
      Ss[i][j] = __expf(Ss[i][j] - m1[i]);
    }
  }
  __syncthreads();
  int h = t & 127, ch0 = t >> 7;
  float accd[16];
  #pragma unroll
  for (int r = 0; r < 16; r++) accd[r] = 0.f;
  for (int j4 = 0; j4 < 32; j4++) {
    float4 sv = *(const float4*)&Ss[h][j4*4];
    #pragma unroll
    for (int r = 0; r < 16; r++) {
      float4 vv = *(const float4*)&Vds[ch0 + 2*r][j4*4];
      accd[r] += sv.x*vv.x + sv.y*vv.y + sv.z*vv.z + sv.w*vv.w;
    }
  }
  float il1 = 1.f / l1[h];
  __syncthreads();
  {
    float m2j = m2[j], il2 = 1.f / l2[j];
    int i0 = t >> 7;
    for (int r = 0; r < 64; r++) {
      int i = i0 + 2*r;
      Ss[i][j] = Ss[i][j] * __expf(m1[i] - m2j) * il2;
    }
  }
  __syncthreads();
  float accu[16];
  #pragma unroll
  for (int r = 0; r < 16; r++) accu[r] = 0.f;
  for (int i4 = 0; i4 < 32; i4++) {
    float p0 = Ss[i4*4+0][h], p1 = Ss[i4*4+1][h], p2 = Ss[i4*4+2][h], p3 = Ss[i4*4+3][h];
    #pragma unroll
    for (int r = 0; r < 16; r++) {
      float4 vv = *(const float4*)&Vus[ch0 + 2*r][i4*4];
      accu[r] += p0*vv.x + p1*vv.y + p2*vv.z + p3*vv.w;
    }
  }
  #pragma unroll
  for (int r = 0; r < 16; r++) {
    int c = ch0 + 2*r;
    float ruv = ws[WS_RU + b*96 + 32 + c];
    float rdv = ws[WS_RD + b*96 + 32 + c];
    float cav = ws[WS_CADD + b*96 + 32 + c];
    size_t off = ((size_t)(b*NC + 32 + c)*NH + hrow)*NWID + h;
    out[off] = accd[r]*il1*ruv + accu[r]*rdv + cav + xu[off] + xd[off];
  }
}

// ---------------- channel attention: score accumulation ----------------
__global__ __launch_bounds__(256) void attn_c1(float* __restrict__ ws) {
  __shared__ float qs[32][260], ks[32][260];
  int b = blockIdx.x >> 6, chunk = blockIdx.x & 63;
  int n0 = chunk * 256;
  int t = threadIdx.x;
  const float* qp = ws + WS_QKVU + ((size_t)b*NCO + 64)*NN + n0;
  const float* kp = ws + WS_QKVD + ((size_t)b*NCO + 64)*NN + n0;
  for (int r = 0; r < 8; r++) {
    int idx = t + r*256;
    int c = idx >> 6, n4 = idx & 63;
    *(float4*)&qs[c][n4*4] = *(const float4*)(qp + (size_t)c*NN + n4*4);
    *(float4*)&ks[c][n4*4] = *(const float4*)(kp + (size_t)c*NN + n4*4);
  }
  __syncthreads();
  int d = t & 31, cb = t >> 5;
  float a[4] = {0.f,0.f,0.f,0.f};
  for (int n4 = 0; n4 < 64; n4++) {
    float4 kv = *(const float4*)&ks[d][n4*4];
    #pragma unroll
    for (int r = 0; r < 4; r++) {
      float4 qv = *(const float4*)&qs[cb + 8*r][n4*4];
      a[r] += qv.x*kv.x + qv.y*kv.y + qv.z*kv.z + qv.w*kv.w;
    }
  }
  #pragma unroll
  for (int r = 0; r < 4; r++)
    atomicAdd(&ws[WS_SC + b*1024 + (cb + 8*r)*32 + d], a[r]);
}

// ---------------- channel attention: softmax ----------------
__global__ void attn_c2(float* __restrict__ ws, const float* __restrict__ scale_p) {
  int b = blockIdx.x, c = threadIdx.x;
  if (c >= 32) return;
  float sc = scale_p[0];
  float row[32];
  float m = -3.0e38f;
  for (int d = 0; d < 32; d++) { row[d] = ws[WS_SC + b*1024 + c*32 + d] * sc; m = fmaxf(m, row[d]); }
  float s = 0.f;
  for (int d = 0; d < 32; d++) { row[d] = __expf(row[d] - m); s += row[d]; }
  float inv = 1.f / s;
  for (int d = 0; d < 32; d++) ws[WS_AC + b*1024 + c*32 + d] = row[d]*inv;
}

// ---------------- channel attention: apply + epilogue (out channels 64..95) ----------------
__global__ __launch_bounds__(256) void attn_c3(float* __restrict__ ws,
    const float* __restrict__ xu, const float* __restrict__ xd,
    float* __restrict__ out) {
  __shared__ float AsT[32][36];
  __shared__ float ruL[32], rdL[32], caL[32];
  int b = blockIdx.x >> 6, chunk = blockIdx.x & 63;
  int t = threadIdx.x;
  for (int r = 0; r < 4; r++) {
    int idx = t + r*256;
    int c = idx >> 5, d = idx & 31;
    AsT[d][c] = ws[WS_AC + b*1024 + idx];
  }
  if (t < 32) {
    ruL[t] = ws[WS_RU + b*96 + 64 + t];
    rdL[t] = ws[WS_RD + b*96 + 64 + t];
    caL[t] = ws[WS_CADD + b*96 + 64 + t];
  }
  __syncthreads();
  int n = chunk*256 + t;
  const float* vdp = ws + WS_QKVD + ((size_t)b*NCO + 160)*NN + n;
  const float* vup = ws + WS_QKVU + ((size_t)b*NCO + 160)*NN + n;
  float acc1[32], acc2[32];
  #pragma unroll
  for (int c2 = 0; c2 < 32; c2++) { acc1[c2]=0.f; acc2[c2]=0.f; }
  for (int d = 0; d < 32; d++) {
    float vd = vdp[(size_t)d*NN];
    float vu = vup[(size_t)d*NN];
    #pragma unroll
    for (int c4 = 0; c4 < 8; c4++) {
      float4 av = *(const float4*)&AsT[d][c4*4];
      acc1[c4*4+0] += av.x*vd; acc2[c4*4+0] += av.x*vu;
      acc1[c4*4+1] += av.y*vd; acc2[c4*4+1] += av.y*vu;
      acc1[c4*4+2] += av.z*vd; acc2[c4*4+2] += av.z*vu;
      acc1[c4*4+3] += av.w*vd; acc2[c4*4+3] += av.w*vu;
    }
  }
  size_t base = ((size_t)(b*NC) + 64)*NN + n;
  #pragma unroll
  for (int c2 = 0; c2 < 32; c2++) {
    size_t off = base + (size_t)c2*NN;
    out[off] = acc1[c2]*ruL[c2] + acc2[c2]*rdL[c2] + caL[c2] + xu[off] + xd[off];
  }
}

extern "C" void kernel_launch(void* const* d_in, const int* in_sizes, int n_in,
                              void* d_out, int out_size, void* d_ws, size_t ws_size,
                              hipStream_t stream) {
  (void)in_sizes; (void)n_in; (void)out_size; (void)ws_size;
  const float* xu   = (const float*)d_in[0];
  const float* xd   = (const float*)d_in[1];
  const float* nwu  = (const float*)d_in[2];
  const float* nbu  = (const float*)d_in[3];
  const float* m1wu = (const float*)d_in[4];
  const float* m1bu = (const float*)d_in[5];
  const float* m2wu = (const float*)d_in[6];
  const float* m2bu = (const float*)d_in[7];
  const float* nwd  = (const float*)d_in[8];
  const float* nbd  = (const float*)d_in[9];
  const float* m1wd = (const float*)d_in[10];
  const float* m1bd = (const float*)d_in[11];
  const float* m2wd = (const float*)d_in[12];
  const float* m2bd = (const float*)d_in[13];
  const float* Wqu  = (const float*)d_in[14];
  const float* bqu  = (const float*)d_in[15];
  const float* Wqd  = (const float*)d_in[16];
  const float* bqd  = (const float*)d_in[17];
  const float* sch  = (const float*)d_in[18];
  const float* scw  = (const float*)d_in[19];
  const float* scc  = (const float*)d_in[20];
  float* ws  = (float*)d_ws;
  float* out = (float*)d_out;

  hipMemsetAsync(d_ws, 0, 8224*sizeof(float), stream);
  reduce_stats<<<1024, 256, 0, stream>>>(xu, xd, ws);
  compute_params<<<1, 256, 0, stream>>>(ws, nwu, nbu, m1wu, m1bu, m2wu, m2bu,
                                        nwd, nbd, m1wd, m1bd, m2wd, m2bd,
                                        Wqu, bqu, Wqd, bqd);
  compute_wprime<<<1152, 256, 0, stream>>>(ws, Wqu, Wqd);
  qkv_gemm<<<2048, 256, 0, stream>>>(ws, xu, xd);
  attn_h<<<1024, 256, 0, stream>>>(ws, xu, xd, out, sch);
  attn_w<<<1024, 256, 0, stream>>>(ws, xu, xd, out, scw);
  attn_c1<<<512, 256, 0, stream>>>(ws);
  attn_c2<<<8, 64, 0, stream>>>(ws, scc);
  attn_c3<<<512, 256, 0, stream>>>(ws, xu, xd, out);
}

// Round 2
// 402.498 us; speedup vs baseline: 2.1816x; 2.1816x over previous
//
#include <hip/hip_runtime.h>
#include <math.h>

#define NB 8
#define NC 96
#define NH 128
#define NWID 128
#define NN (NH*NWID)      // 16384
#define NCO 192
#define NM (NC*NN)        // 1572864

// ---------------- workspace layout (float offsets) ----------------
#define WS_SUMS   0                     // [2][8][2]  (zeroed)
#define WS_SC     32                    // [8][32][32] (zeroed)
#define WS_AC     8224                  // [8][32][32]
#define WS_SU     16416                 // [8][96]
#define WS_TU     17184
#define WS_SD     17952
#define WS_TD     18720
#define WS_RU     19488                 // resc_u [8][96]
#define WS_RD     20256                 // resc_d
#define WS_CADD   21024                 // rebias_u+rebias_d
#define WS_BPU    21792                 // eff bias [8][192]
#define WS_BPD    23328
#define WS_WPU    24864                 // eff W transposed [8][96][192] fp32
#define WS_WPD    172320
#define WS_QKV16  327680                // ushort region: 2 tensors x 25165824 u16 (bf16 qkv [b][192][16384])
#define QKV16_D   25165824ull
#define WS_SLABS  25493504              // ushort region base: mfma-ready slabs
#define OFF_QH    0ull                  // [8][128w][128h][40c]
#define OFF_KH    5242880ull
#define OFF_QW    10485760ull           // [8][128h][128w][40c]
#define OFF_KW    15728640ull
#define OFF_VHU   20971520ull           // [8][128w][32c][136h]
#define OFF_VHD   25427968ull
#define OFF_VWU   29884416ull           // [8][128h][32c][136w]
#define OFF_VWD   34340864ull
#define WS_OH     44892160              // fp32 [8][128w][32c][128h] h-attn staging

typedef __attribute__((ext_vector_type(8))) short bf16x8;
typedef __attribute__((ext_vector_type(4))) float f32x4;

static __device__ __forceinline__ float bf2f(ushort u){ return __uint_as_float(((uint)u) << 16); }
static __device__ __forceinline__ ushort f2bf(float f){
  uint b = __float_as_uint(f);
  return (ushort)((b + 0x7fffu + ((b >> 16) & 1u)) >> 16);
}
static __device__ __forceinline__ bf16x8 ldfrag(const ushort* p){
  union { uint4 u; bf16x8 b; } cv; cv.u = *(const uint4*)p; return cv.b;
}

// ---------------- stats reduction: per-sample sum & sumsq ----------------
__global__ __launch_bounds__(256) void reduce_stats(const float* __restrict__ xu,
                                                    const float* __restrict__ xd,
                                                    float* __restrict__ ws) {
  int blk = blockIdx.x;                // 2*8*64
  int tensor = blk >> 9;
  int b = (blk >> 6) & 7;
  int chunk = blk & 63;
  const float* x = tensor ? xd : xu;
  const float4* p = (const float4*)(x + (size_t)b*NM + (size_t)chunk*(NM/64));
  float s = 0.f, sq = 0.f;
  for (int r = 0; r < 24; r++) {
    float4 v = p[threadIdx.x + r*256];
    s  += v.x + v.y + v.z + v.w;
    sq += v.x*v.x + v.y*v.y + v.z*v.z + v.w*v.w;
  }
  for (int o = 32; o; o >>= 1) { s += __shfl_down(s, o); sq += __shfl_down(sq, o); }
  __shared__ float ls[8];
  int wv = threadIdx.x >> 6, ln = threadIdx.x & 63;
  if (ln == 0) { ls[wv*2] = s; ls[wv*2+1] = sq; }
  __syncthreads();
  if (threadIdx.x == 0) {
    s  = ls[0] + ls[2] + ls[4] + ls[6];
    sq = ls[1] + ls[3] + ls[5] + ls[7];
    atomicAdd(&ws[WS_SUMS + (tensor*8 + b)*2],     s);
    atomicAdd(&ws[WS_SUMS + (tensor*8 + b)*2 + 1], sq);
  }
}

// ---------------- derived params ----------------
__global__ void compute_params(float* __restrict__ ws,
    const float* __restrict__ nwu, const float* __restrict__ nbu,
    const float* __restrict__ m1wu, const float* __restrict__ m1bu,
    const float* __restrict__ m2wu, const float* __restrict__ m2bu,
    const float* __restrict__ nwd, const float* __restrict__ nbd,
    const float* __restrict__ m1wd, const float* __restrict__ m1bd,
    const float* __restrict__ m2wd, const float* __restrict__ m2bd,
    const float* __restrict__ Wqu, const float* __restrict__ bqu,
    const float* __restrict__ Wqd, const float* __restrict__ bqd) {
  __shared__ float meanL[16], stdL[16];
  __shared__ float tuL[768], tdL[768];
  int t = threadIdx.x;
  if (t < 16) {
    float s = ws[WS_SUMS + t*2], sq = ws[WS_SUMS + t*2 + 1];
    const float inv = 1.f / (float)NM;
    float mean = s * inv;
    float var  = sq * inv - mean*mean;
    meanL[t] = mean;
    stdL[t]  = sqrtf(var + 1e-5f);
  }
  __syncthreads();
  for (int idx = t; idx < 768; idx += 256) {
    int b = idx / 96, c = idx % 96;
    float mu = meanL[b],   su = stdL[b];
    float md = meanL[8+b], sd = stdL[8+b];
    float scu = nwu[c] / su;
    float scd = nwd[c] / sd;
    float tcu = nbu[c] - mu*scu;
    float tcd = nbd[c] - md*scd;
    tuL[idx] = tcu; tdL[idx] = tcd;
    ws[WS_SU+idx] = scu; ws[WS_TU+idx] = tcu;
    ws[WS_SD+idx] = scd; ws[WS_TD+idx] = tcd;
    ws[WS_RU+idx] = su*m1wu[c] + m1bu[c];
    ws[WS_RD+idx] = sd*m1wd[c] + m1bd[c];
    ws[WS_CADD+idx] = (mu*m2wu[c] + m2bu[c]) + (md*m2wd[c] + m2bd[c]);
  }
  __syncthreads();
  for (int idx = t; idx < 3072; idx += 256) {
    int tensor = idx / 1536;
    int r = idx % 1536;
    int b = r / 192, o = r % 192;
    const float* Wq = tensor ? Wqd : Wqu;
    const float* tt = tensor ? tdL : tuL;
    float acc = tensor ? bqd[o] : bqu[o];
    for (int i = 0; i < 96; i++) acc += Wq[o*96 + i] * tt[b*96 + i];
    ws[(tensor ? WS_BPD : WS_BPU) + r] = acc;
  }
}

// ---------------- W' = W * scale, stored transposed [b][i][o] fp32 ----------------
__global__ __launch_bounds__(256) void compute_wprime(float* __restrict__ ws,
    const float* __restrict__ Wqu, const float* __restrict__ Wqd) {
  int idx = blockIdx.x*256 + threadIdx.x;
  int tensor = idx / 147456;
  int r = idx % 147456;
  int b  = r / 18432;
  int r2 = r % 18432;
  int i  = r2 / 192, o = r2 % 192;
  const float* Wq = tensor ? Wqd : Wqu;
  const float* s  = ws + (tensor ? WS_SD : WS_SU);
  ws[(tensor ? WS_WPD : WS_WPU) + r] = Wq[o*96 + i] * s[b*96 + i];
}

// ---------------- qkv GEMM (fp32 math, bf16 output) ----------------
__global__ __launch_bounds__(256) void qkv_gemm(float* __restrict__ ws,
    const float* __restrict__ xu, const float* __restrict__ xd) {
  __shared__ float xs[96][128];
  __shared__ float wst[96][192];
  int blk = blockIdx.x;
  int tensor = blk >> 10;
  int rem = blk & 1023;
  int b = rem >> 7;
  int nt = rem & 127;
  const float* x  = tensor ? xd : xu;
  const float* wp = ws + (tensor ? WS_WPD : WS_WPU) + (size_t)b*18432;
  const float* bp = ws + (tensor ? WS_BPD : WS_BPU) + b*192;
  ushort* outq16 = (ushort*)(ws + WS_QKV16) + (tensor ? QKV16_D : 0) + (size_t)b*NCO*NN;
  int t = threadIdx.x;
  for (int r = 0; r < 12; r++) {
    int idx = t + r*256;
    int i = idx >> 5, c4 = idx & 31;
    *(float4*)&xs[i][c4*4] = *(const float4*)(x + (size_t)b*NM + (size_t)i*NN + nt*128 + c4*4);
  }
  {
    const float4* wsrc = (const float4*)wp;
    float4* wdst = (float4*)&wst[0][0];
    for (int r = 0; r < 18; r++) wdst[t + r*256] = wsrc[t + r*256];
  }
  __syncthreads();
  int n4 = t & 31, og = t >> 5;
  float4 acc[24];
  #pragma unroll
  for (int k = 0; k < 24; k++) acc[k] = make_float4(0.f,0.f,0.f,0.f);
  for (int i = 0; i < 96; i++) {
    float4 xv = *(const float4*)&xs[i][n4*4];
    const float* wrow = &wst[i][og*24];
    #pragma unroll
    for (int k6 = 0; k6 < 6; k6++) {
      float4 wv = *(const float4*)&wrow[k6*4];
      acc[k6*4+0].x += wv.x*xv.x; acc[k6*4+0].y += wv.x*xv.y; acc[k6*4+0].z += wv.x*xv.z; acc[k6*4+0].w += wv.x*xv.w;
      acc[k6*4+1].x += wv.y*xv.x; acc[k6*4+1].y += wv.y*xv.y; acc[k6*4+1].z += wv.y*xv.z; acc[k6*4+1].w += wv.y*xv.w;
      acc[k6*4+2].x += wv.z*xv.x; acc[k6*4+2].y += wv.z*xv.y; acc[k6*4+2].z += wv.z*xv.z; acc[k6*4+2].w += wv.z*xv.w;
      acc[k6*4+3].x += wv.w*xv.x; acc[k6*4+3].y += wv.w*xv.y; acc[k6*4+3].z += wv.w*xv.z; acc[k6*4+3].w += wv.w*xv.w;
    }
  }
  #pragma unroll
  for (int ko = 0; ko < 24; ko++) {
    int o = og*24 + ko;
    float bb = bp[o];
    float4 v = acc[ko];
    v.x += bb; v.y += bb; v.z += bb; v.w += bb;
    uint2 pk;
    pk.x = (uint)f2bf(v.x) | ((uint)f2bf(v.y) << 16);
    pk.y = (uint)f2bf(v.z) | ((uint)f2bf(v.w) << 16);
    *(uint2*)(outq16 + (size_t)o*NN + nt*128 + n4*4) = pk;
  }
}

// ---------------- prep: brick transpose qkv(bf16) -> mfma slabs ----------------
__global__ __launch_bounds__(256) void qkv_prep(float* __restrict__ ws) {
  __shared__ __align__(16) ushort Br[16*1320];   // [16c][33h][40w] c-stride 1320
  int bid = blockIdx.x;                           // 8 roles * 2cb * 8b * 4hb * 4wb = 2048
  int role = bid >> 8;
  int r = bid & 255;
  int cb = r >> 7, b = (r >> 4) & 7, hb = (r >> 2) & 3, wb = r & 3;
  const int chbt[8]  = {0,0,32,32,96,96,128,128};
  const int tenst[8] = {0,1,0,1,0,1,0,1};
  const int modet[8] = {0,0,1,1,2,2,3,3};
  const size_t dstofft[8] = {OFF_QH,OFF_KH,OFF_QW,OFF_KW,OFF_VHU,OFF_VHD,OFF_VWU,OFF_VWD};
  int mode = modet[role];
  const ushort* qkv16 = (const ushort*)(ws + WS_QKV16);
  const ushort* src = qkv16 + (tenst[role] ? QKV16_D : 0)
                    + (size_t)b*NCO*NN + (size_t)(chbt[role] + cb*16)*NN;
  ushort* dst = (ushort*)(ws + WS_SLABS) + dstofft[role];
  int t = threadIdx.x;
  for (int k = 0; k < 8; k++) {
    int idx = t + k*256;                          // 2048 = 16c*32h*4(w8)
    int c = idx >> 7, h = (idx >> 2) & 31, w8 = idx & 3;
    uint4 v = *(const uint4*)(src + (size_t)c*NN + (size_t)(hb*32 + h)*NWID + wb*32 + w8*8);
    *(uint4*)&Br[c*1320 + h*40 + w8*8] = v;
  }
  __syncthreads();
  if (mode <= 1) {
    for (int k = 0; k < 4; k++) {
      int idx = t + k*256;                        // 1024 = 32w*32h
      int p = idx >> 5, q = idx & 31;             // p=w, q=h
      uint uu[8];
      #pragma unroll
      for (int cc = 0; cc < 8; cc++) {
        ushort a0 = Br[(2*cc)*1320 + q*40 + p];
        ushort a1 = Br[(2*cc+1)*1320 + q*40 + p];
        uu[cc] = (uint)a0 | ((uint)a1 << 16);
      }
      size_t o = (mode == 0)
        ? ((size_t)(b*128 + wb*32 + p)*128 + hb*32 + q)*40
        : ((size_t)(b*128 + hb*32 + q)*128 + wb*32 + p)*40;
      *(uint4*)(dst + o + cb*16)     = make_uint4(uu[0],uu[1],uu[2],uu[3]);
      *(uint4*)(dst + o + cb*16 + 8) = make_uint4(uu[4],uu[5],uu[6],uu[7]);
    }
  } else if (mode == 2) {
    for (int k = 0; k < 2; k++) {
      int idx = t + k*256;                        // 512 = 32w*16c
      int w = idx >> 4, c = idx & 15;
      uint uu[16];
      #pragma unroll
      for (int hh = 0; hh < 16; hh++) {
        ushort a0 = Br[c*1320 + (2*hh)*40 + w];
        ushort a1 = Br[c*1320 + (2*hh+1)*40 + w];
        uu[hh] = (uint)a0 | ((uint)a1 << 16);
      }
      size_t o = ((size_t)(b*128 + wb*32 + w)*32 + cb*16 + c)*136 + hb*32;
      *(uint4*)(dst + o)      = make_uint4(uu[0],uu[1],uu[2],uu[3]);
      *(uint4*)(dst + o + 8)  = make_uint4(uu[4],uu[5],uu[6],uu[7]);
      *(uint4*)(dst + o + 16) = make_uint4(uu[8],uu[9],uu[10],uu[11]);
      *(uint4*)(dst + o + 24) = make_uint4(uu[12],uu[13],uu[14],uu[15]);
    }
  } else {
    for (int k = 0; k < 2; k++) {
      int idx = t + k*256;                        // 512 = 32h*16c
      int h = idx >> 4, c = idx & 15;
      size_t o = ((size_t)(b*128 + hb*32 + h)*32 + cb*16 + c)*136 + wb*32;
      const uint4* s = (const uint4*)&Br[c*1320 + h*40];
      *(uint4*)(dst + o)      = s[0];
      *(uint4*)(dst + o + 8)  = s[1];
      *(uint4*)(dst + o + 16) = s[2];
      *(uint4*)(dst + o + 24) = s[3];
    }
  }
}

// ---------------- MFMA spatial attention (AXIS 0 = h, 1 = w) ----------------
template<int AXIS>
__global__ __launch_bounds__(256) void attn_mfma(float* __restrict__ ws,
    const float* __restrict__ xu, const float* __restrict__ xd,
    float* __restrict__ out, const float* __restrict__ scale_p) {
  __shared__ __align__(16) ushort Qs[128*40];
  __shared__ __align__(16) ushort Ks[128*40];
  __shared__ __align__(16) ushort Vds[32*136];
  __shared__ __align__(16) ushort Vus[32*136];
  __shared__ __align__(16) ushort Pl[128*136];
  __shared__ float m1s[128], l1s[128];
  const int b = blockIdx.x >> 7, p2 = blockIdx.x & 127;
  const int t = threadIdx.x;
  const int wv = t >> 6, lid = t & 63, l15 = lid & 15, l4 = lid >> 4;
  const ushort* slab = (const ushort*)(ws + WS_SLABS);
  const ushort* qsrc  = slab + (AXIS ? OFF_QW : OFF_QH) + (size_t)(b*128 + p2)*5120;
  const ushort* ksrc  = slab + (AXIS ? OFF_KW : OFF_KH) + (size_t)(b*128 + p2)*5120;
  const ushort* vdsrc = slab + (AXIS ? OFF_VWD : OFF_VHD) + (size_t)(b*128 + p2)*4352;
  const ushort* vusrc = slab + (AXIS ? OFF_VWU : OFF_VHU) + (size_t)(b*128 + p2)*4352;
  for (int i = t; i < 2368; i += 256) {
    const uint4* s; uint4* d;
    if (i < 640)       { s = (const uint4*)qsrc + i;          d = (uint4*)Qs + i; }
    else if (i < 1280) { s = (const uint4*)ksrc + (i-640);    d = (uint4*)Ks + (i-640); }
    else if (i < 1824) { s = (const uint4*)vdsrc + (i-1280);  d = (uint4*)Vds + (i-1280); }
    else               { s = (const uint4*)vusrc + (i-1824);  d = (uint4*)Vus + (i-1824); }
    *d = *s;
  }
  const float sc = scale_p[0];
  const int cbas = AXIS ? 32 : 0;
  float ruv0 = ws[WS_RU + b*96 + cbas + l15];
  float ruv1 = ws[WS_RU + b*96 + cbas + 16 + l15];
  float rdv0 = ws[WS_RD + b*96 + cbas + l15];
  float rdv1 = ws[WS_RD + b*96 + cbas + 16 + l15];
  __syncthreads();

  f32x4 z4 = {0.f,0.f,0.f,0.f};
  f32x4 s1[2][8];
  // ---- S1[i][j] = sum_c Q[i][c] K[j][c], wave owns i-tiles {2wv,2wv+1} ----
  {
    bf16x8 bfr[8];
    #pragma unroll
    for (int tj = 0; tj < 8; tj++) bfr[tj] = ldfrag(&Ks[(tj*16 + l15)*40 + l4*8]);
    #pragma unroll
    for (int ti = 0; ti < 2; ti++) {
      bf16x8 a = ldfrag(&Qs[((2*wv+ti)*16 + l15)*40 + l4*8]);
      #pragma unroll
      for (int tj = 0; tj < 8; tj++)
        s1[ti][tj] = __builtin_amdgcn_mfma_f32_16x16x32_bf16(a, bfr[tj], z4, 0, 0, 0);
    }
  }
  // ---- row softmax over j; write P1 bf16 ----
  #pragma unroll
  for (int ti = 0; ti < 2; ti++) {
    #pragma unroll
    for (int r = 0; r < 4; r++) {
      float mx = -3.0e38f;
      #pragma unroll
      for (int tj = 0; tj < 8; tj++) { float v = s1[ti][tj][r]*sc; s1[ti][tj][r] = v; mx = fmaxf(mx, v); }
      mx = fmaxf(mx, __shfl_xor(mx, 1)); mx = fmaxf(mx, __shfl_xor(mx, 2));
      mx = fmaxf(mx, __shfl_xor(mx, 4)); mx = fmaxf(mx, __shfl_xor(mx, 8));
      float sm = 0.f;
      #pragma unroll
      for (int tj = 0; tj < 8; tj++) { float e = __expf(s1[ti][tj][r] - mx); s1[ti][tj][r] = e; sm += e; }
      sm += __shfl_xor(sm, 1); sm += __shfl_xor(sm, 2); sm += __shfl_xor(sm, 4); sm += __shfl_xor(sm, 8);
      int row = 32*wv + ti*16 + l4*4 + r;
      if (l15 == 0) { m1s[row] = mx; l1s[row] = sm; }
      float inv = __fdividef(1.f, sm);
      #pragma unroll
      for (int tj = 0; tj < 8; tj++) Pl[row*136 + tj*16 + l15] = f2bf(s1[ti][tj][r]*inv);
    }
  }
  __syncthreads();
  // ---- PV1: o1[i][c] = sum_j P1[i][j] Vd[c][j] ----
  f32x4 o1[2][2] = {{z4,z4},{z4,z4}};
  #pragma unroll
  for (int ks = 0; ks < 4; ks++) {
    bf16x8 bv0 = ldfrag(&Vds[l15*136 + ks*32 + l4*8]);
    bf16x8 bv1 = ldfrag(&Vds[(16 + l15)*136 + ks*32 + l4*8]);
    #pragma unroll
    for (int mt = 0; mt < 2; mt++) {
      bf16x8 a = ldfrag(&Pl[((2*wv+mt)*16 + l15)*136 + ks*32 + l4*8]);
      o1[mt][0] = __builtin_amdgcn_mfma_f32_16x16x32_bf16(a, bv0, o1[mt][0], 0, 0, 0);
      o1[mt][1] = __builtin_amdgcn_mfma_f32_16x16x32_bf16(a, bv1, o1[mt][1], 0, 0, 0);
    }
  }
  // ---- S2[j][i] = S1^T via mfma(K, Q) ----
  {
    bf16x8 bq[8];
    #pragma unroll
    for (int it = 0; it < 8; it++) bq[it] = ldfrag(&Qs[(it*16 + l15)*40 + l4*8]);
    #pragma unroll
    for (int tjt = 0; tjt < 2; tjt++) {
      bf16x8 a = ldfrag(&Ks[((2*wv+tjt)*16 + l15)*40 + l4*8]);
      #pragma unroll
      for (int it = 0; it < 8; it++)
        s1[tjt][it] = __builtin_amdgcn_mfma_f32_16x16x32_bf16(a, bq[it], z4, 0, 0, 0);
    }
  }
  // ---- pass-2 softmax (values left in regs) ----
  if (AXIS == 1) {
    // width attention: independent row softmax of S^T (= column softmax of S)
    #pragma unroll
    for (int tjt = 0; tjt < 2; tjt++) {
      #pragma unroll
      for (int r = 0; r < 4; r++) {
        float mx = -3.0e38f;
        #pragma unroll
        for (int it = 0; it < 8; it++) { float v = s1[tjt][it][r]*sc; s1[tjt][it][r] = v; mx = fmaxf(mx, v); }
        mx = fmaxf(mx, __shfl_xor(mx, 1)); mx = fmaxf(mx, __shfl_xor(mx, 2));
        mx = fmaxf(mx, __shfl_xor(mx, 4)); mx = fmaxf(mx, __shfl_xor(mx, 8));
        float sm = 0.f;
        #pragma unroll
        for (int it = 0; it < 8; it++) { float e = __expf(s1[tjt][it][r] - mx); s1[tjt][it][r] = e; sm += e; }
        sm += __shfl_xor(sm, 1); sm += __shfl_xor(sm, 2); sm += __shfl_xor(sm, 4); sm += __shfl_xor(sm, 8);
        float inv = __fdividef(1.f, sm);
        #pragma unroll
        for (int it = 0; it < 8; it++) s1[tjt][it][r] *= inv;
      }
    }
  } else {
    // height attention: reuse pass-1 row stats (same softmax, transposed use)
    float mi[8], li[8];
    #pragma unroll
    for (int it = 0; it < 8; it++) {
      mi[it] = m1s[it*16 + l15];
      li[it] = __fdividef(1.f, l1s[it*16 + l15]);
    }
    #pragma unroll
    for (int tjt = 0; tjt < 2; tjt++)
      #pragma unroll
      for (int it = 0; it < 8; it++)
        #pragma unroll
        for (int r = 0; r < 4; r++)
          s1[tjt][it][r] = __expf(s1[tjt][it][r]*sc - mi[it]) * li[it];
  }
  __syncthreads();   // all PV1 reads of Pl done
  #pragma unroll
  for (int tjt = 0; tjt < 2; tjt++)
    #pragma unroll
    for (int r = 0; r < 4; r++) {
      int row = 32*wv + tjt*16 + l4*4 + r;
      #pragma unroll
      for (int it = 0; it < 8; it++) Pl[row*136 + it*16 + l15] = f2bf(s1[tjt][it][r]);
    }
  __syncthreads();
  // ---- PV2: o2[j][c] = sum_i P2[j][i] Vu[c][i] ----
  f32x4 o2[2][2] = {{z4,z4},{z4,z4}};
  #pragma unroll
  for (int ks = 0; ks < 4; ks++) {
    bf16x8 bv0 = ldfrag(&Vus[l15*136 + ks*32 + l4*8]);
    bf16x8 bv1 = ldfrag(&Vus[(16 + l15)*136 + ks*32 + l4*8]);
    #pragma unroll
    for (int mt = 0; mt < 2; mt++) {
      bf16x8 a = ldfrag(&Pl[((2*wv+mt)*16 + l15)*136 + ks*32 + l4*8]);
      o2[mt][0] = __builtin_amdgcn_mfma_f32_16x16x32_bf16(a, bv0, o2[mt][0], 0, 0, 0);
      o2[mt][1] = __builtin_amdgcn_mfma_f32_16x16x32_bf16(a, bv1, o2[mt][1], 0, 0, 0);
    }
  }
  __syncthreads();   // PV2 reads done; reuse Pl as fp32 stage [32][132]
  float* St = (float*)Pl;
  #pragma unroll
  for (int mt = 0; mt < 2; mt++)
    #pragma unroll
    for (int nt = 0; nt < 2; nt++) {
      float ru = nt ? ruv1 : ruv0;
      float rd = nt ? rdv1 : rdv0;
      float4 vv;
      vv.x = o1[mt][nt][0]*ru + o2[mt][nt][0]*rd;
      vv.y = o1[mt][nt][1]*ru + o2[mt][nt][1]*rd;
      vv.z = o1[mt][nt][2]*ru + o2[mt][nt][2]*rd;
      vv.w = o1[mt][nt][3]*ru + o2[mt][nt][3]*rd;
      *(float4*)&St[(nt*16 + l15)*132 + (2*wv+mt)*16 + l4*4] = vv;
    }
  __syncthreads();
  if (AXIS == 1) {
    for (int k = 0; k < 4; k++) {
      int idx = t + k*256;
      int c = idx >> 5, p4 = idx & 31;
      float4 v = *(const float4*)&St[c*132 + p4*4];
      float ca = ws[WS_CADD + b*96 + 32 + c];
      size_t off = ((size_t)(b*NC + 32 + c)*NH + p2)*NWID + p4*4;
      float4 a = *(const float4*)(xu + off);
      float4 dd = *(const float4*)(xd + off);
      v.x += ca + a.x + dd.x; v.y += ca + a.y + dd.y;
      v.z += ca + a.z + dd.z; v.w += ca + a.w + dd.w;
      *(float4*)(out + off) = v;
    }
  } else {
    float* oh = ws + WS_OH;
    for (int k = 0; k < 4; k++) {
      int idx = t + k*256;
      int c = idx >> 5, p4 = idx & 31;
      float4 v = *(const float4*)&St[c*132 + p4*4];
      *(float4*)(oh + ((size_t)(b*128 + p2)*32 + c)*128 + p4*4) = v;
    }
  }
}

// ---------------- merge h-attn staging into final out (ch 0..31) ----------------
__global__ __launch_bounds__(256) void merge_h(float* __restrict__ ws,
    const float* __restrict__ xu, const float* __restrict__ xd,
    float* __restrict__ out) {
  __shared__ float T[32][33];
  int bid = blockIdx.x;                 // 8b*32c*4ht*4wt = 4096
  int b = bid >> 9, c = (bid >> 4) & 31, ht = (bid >> 2) & 3, wt = bid & 3;
  int t = threadIdx.x;
  const float* oh = ws + WS_OH;
  {
    int w = t >> 3, h4 = t & 7;
    float4 v = *(const float4*)(oh + ((size_t)(b*128 + wt*32 + w)*32 + c)*128 + ht*32 + h4*4);
    T[w][h4*4+0] = v.x; T[w][h4*4+1] = v.y; T[w][h4*4+2] = v.z; T[w][h4*4+3] = v.w;
  }
  __syncthreads();
  {
    int h = t >> 3, w4 = t & 7;
    float ca = ws[WS_CADD + b*96 + c];
    size_t off = ((size_t)(b*NC + c)*NH + ht*32 + h)*NWID + wt*32 + w4*4;
    float4 a = *(const float4*)(xu + off);
    float4 d = *(const float4*)(xd + off);
    float4 v;
    v.x = T[w4*4+0][h] + ca + a.x + d.x;
    v.y = T[w4*4+1][h] + ca + a.y + d.y;
    v.z = T[w4*4+2][h] + ca + a.z + d.z;
    v.w = T[w4*4+3][h] + ca + a.w + d.w;
    *(float4*)(out + off) = v;
  }
}

// ---------------- channel attention: score accumulation (bf16 in) ----------------
__global__ __launch_bounds__(256) void attn_c1(float* __restrict__ ws) {
  __shared__ float qs[32][260], ks[32][260];
  int b = blockIdx.x >> 6, chunk = blockIdx.x & 63;
  int n0 = chunk * 256;
  int t = threadIdx.x;
  const ushort* qkv16 = (const ushort*)(ws + WS_QKV16);
  const ushort* qp = qkv16 + ((size_t)b*NCO + 64)*NN + n0;
  const ushort* kp = qkv16 + QKV16_D + ((size_t)b*NCO + 64)*NN + n0;
  for (int r = 0; r < 4; r++) {
    int idx = t + r*256;                 // 1024 = 32c * 32 chunks of 8
    int c = idx >> 5, n8 = idx & 31;
    uint4 v = *(const uint4*)(qp + (size_t)c*NN + n8*8);
    uint4 w = *(const uint4*)(kp + (size_t)c*NN + n8*8);
    float* q = &qs[c][n8*8];
    float* kk = &ks[c][n8*8];
    q[0] = bf2f((ushort)(v.x & 0xffff)); q[1] = bf2f((ushort)(v.x >> 16));
    q[2] = bf2f((ushort)(v.y & 0xffff)); q[3] = bf2f((ushort)(v.y >> 16));
    q[4] = bf2f((ushort)(v.z & 0xffff)); q[5] = bf2f((ushort)(v.z >> 16));
    q[6] = bf2f((ushort)(v.w & 0xffff)); q[7] = bf2f((ushort)(v.w >> 16));
    kk[0] = bf2f((ushort)(w.x & 0xffff)); kk[1] = bf2f((ushort)(w.x >> 16));
    kk[2] = bf2f((ushort)(w.y & 0xffff)); kk[3] = bf2f((ushort)(w.y >> 16));
    kk[4] = bf2f((ushort)(w.z & 0xffff)); kk[5] = bf2f((ushort)(w.z >> 16));
    kk[6] = bf2f((ushort)(w.w & 0xffff)); kk[7] = bf2f((ushort)(w.w >> 16));
  }
  __syncthreads();
  int d = t & 31, cbq = t >> 5;
  float a[4] = {0.f,0.f,0.f,0.f};
  for (int n4 = 0; n4 < 64; n4++) {
    float4 kv = *(const float4*)&ks[d][n4*4];
    #pragma unroll
    for (int r = 0; r < 4; r++) {
      float4 qv = *(const float4*)&qs[cbq + 8*r][n4*4];
      a[r] += qv.x*kv.x + qv.y*kv.y + qv.z*kv.z + qv.w*kv.w;
    }
  }
  #pragma unroll
  for (int r = 0; r < 4; r++)
    atomicAdd(&ws[WS_SC + b*1024 + (cbq + 8*r)*32 + d], a[r]);
}

// ---------------- channel attention: softmax ----------------
__global__ void attn_c2(float* __restrict__ ws, const float* __restrict__ scale_p) {
  int b = blockIdx.x, c = threadIdx.x;
  if (c >= 32) return;
  float sc = scale_p[0];
  float row[32];
  float m = -3.0e38f;
  for (int d = 0; d < 32; d++) { row[d] = ws[WS_SC + b*1024 + c*32 + d] * sc; m = fmaxf(m, row[d]); }
  float s = 0.f;
  for (int d = 0; d < 32; d++) { row[d] = __expf(row[d] - m); s += row[d]; }
  float inv = 1.f / s;
  for (int d = 0; d < 32; d++) ws[WS_AC + b*1024 + c*32 + d] = row[d]*inv;
}

// ---------------- channel attention: apply + epilogue (ch 64..95) ----------------
__global__ __launch_bounds__(256) void attn_c3(float* __restrict__ ws,
    const float* __restrict__ xu, const float* __restrict__ xd,
    float* __restrict__ out) {
  __shared__ float AsT[32][36];
  __shared__ float ruL[32], rdL[32], caL[32];
  int b = blockIdx.x >> 6, chunk = blockIdx.x & 63;
  int t = threadIdx.x;
  for (int r = 0; r < 4; r++) {
    int idx = t + r*256;
    int c = idx >> 5, d = idx & 31;
    AsT[d][c] = ws[WS_AC + b*1024 + idx];
  }
  if (t < 32) {
    ruL[t] = ws[WS_RU + b*96 + 64 + t];
    rdL[t] = ws[WS_RD + b*96 + 64 + t];
    caL[t] = ws[WS_CADD + b*96 + 64 + t];
  }
  __syncthreads();
  int n = chunk*256 + t;
  const ushort* qkv16 = (const ushort*)(ws + WS_QKV16);
  const ushort* vdp = qkv16 + QKV16_D + ((size_t)b*NCO + 160)*NN + n;
  const ushort* vup = qkv16 + ((size_t)b*NCO + 160)*NN + n;
  float acc1[32], acc2[32];
  #pragma unroll
  for (int c2 = 0; c2 < 32; c2++) { acc1[c2]=0.f; acc2[c2]=0.f; }
  for (int d = 0; d < 32; d++) {
    float vd = bf2f(vdp[(size_t)d*NN]);
    float vu = bf2f(vup[(size_t)d*NN]);
    #pragma unroll
    for (int c4 = 0; c4 < 8; c4++) {
      float4 av = *(const float4*)&AsT[d][c4*4];
      acc1[c4*4+0] += av.x*vd; acc2[c4*4+0] += av.x*vu;
      acc1[c4*4+1] += av.y*vd; acc2[c4*4+1] += av.y*vu;
      acc1[c4*4+2] += av.z*vd; acc2[c4*4+2] += av.z*vu;
      acc1[c4*4+3] += av.w*vd; acc2[c4*4+3] += av.w*vu;
    }
  }
  size_t base = ((size_t)(b*NC) + 64)*NN + n;
  #pragma unroll
  for (int c2 = 0; c2 < 32; c2++) {
    size_t off = base + (size_t)c2*NN;
    out[off] = acc1[c2]*ruL[c2] + acc2[c2]*rdL[c2] + caL[c2] + xu[off] + xd[off];
  }
}

extern "C" void kernel_launch(void* const* d_in, const int* in_sizes, int n_in,
                              void* d_out, int out_size, void* d_ws, size_t ws_size,
                              hipStream_t stream) {
  (void)in_sizes; (void)n_in; (void)out_size; (void)ws_size;
  const float* xu   = (const float*)d_in[0];
  const float* xd   = (const float*)d_in[1];
  const float* nwu  = (const float*)d_in[2];
  const float* nbu  = (const float*)d_in[3];
  const float* m1wu = (const float*)d_in[4];
  const float* m1bu = (const float*)d_in[5];
  const float* m2wu = (const float*)d_in[6];
  const float* m2bu = (const float*)d_in[7];
  const float* nwd  = (const float*)d_in[8];
  const float* nbd  = (const float*)d_in[9];
  const float* m1wd = (const float*)d_in[10];
  const float* m1bd = (const float*)d_in[11];
  const float* m2wd = (const float*)d_in[12];
  const float* m2bd = (const float*)d_in[13];
  const float* Wqu  = (const float*)d_in[14];
  const float* bqu  = (const float*)d_in[15];
  const float* Wqd  = (const float*)d_in[16];
  const float* bqd  = (const float*)d_in[17];
  const float* sch  = (const float*)d_in[18];
  const float* scw  = (const float*)d_in[19];
  const float* scc  = (const float*)d_in[20];
  float* ws  = (float*)d_ws;
  float* out = (float*)d_out;

  hipMemsetAsync(d_ws, 0, 8224*sizeof(float), stream);
  reduce_stats<<<1024, 256, 0, stream>>>(xu, xd, ws);
  compute_params<<<1, 256, 0, stream>>>(ws, nwu, nbu, m1wu, m1bu, m2wu, m2bu,
                                        nwd, nbd, m1wd, m1bd, m2wd, m2bd,
                                        Wqu, bqu, Wqd, bqd);
  compute_wprime<<<1152, 256, 0, stream>>>(ws, Wqu, Wqd);
  qkv_gemm<<<2048, 256, 0, stream>>>(ws, xu, xd);
  qkv_prep<<<2048, 256, 0, stream>>>(ws);
  attn_mfma<0><<<1024, 256, 0, stream>>>(ws, xu, xd, out, sch);
  attn_mfma<1><<<1024, 256, 0, stream>>>(ws, xu, xd, out, scw);
  merge_h<<<4096, 256, 0, stream>>>(ws, xu, xd, out);
  attn_c1<<<512, 256, 0, stream>>>(ws);
  attn_c2<<<8, 64, 0, stream>>>(ws, scc);
  attn_c3<<<512, 256, 0, stream>>>(ws, xu, xd, out);
}

// Round 5
// 292.738 us; speedup vs baseline: 2.9996x; 1.3749x over previous
//
#include <hip/hip_runtime.h>
#include <math.h>

#define NB 8
#define NC 96
#define NH 128
#define NWID 128
#define NN (NH*NWID)      // 16384
#define NCO 192
#define NM (NC*NN)        // 1572864

// ---------------- workspace layout (float offsets) ----------------
#define WS_SUMS   0                     // [2][8][2]  (zeroed)
#define WS_SC     32                    // [8][32][32] (zeroed)
#define WS_AC     8224                  // [8][32][32]
#define WS_SU     16416                 // [8][96]
#define WS_TU     17184
#define WS_SD     17952
#define WS_TD     18720
#define WS_RU     19488                 // resc_u [8][96]
#define WS_RD     20256                 // resc_d
#define WS_CADD   21024                 // rebias_u+rebias_d
#define WS_BPU    21792                 // eff bias [8][192]
#define WS_BPD    23328
#define WS_WB16   24864                 // bf16 W' [2][8][192][104] (ushort region, 319488 u16)
#define WS_QKV16  327680                // ushort region: 2 tensors x 25165824 u16 (bf16 qkv [b][192][16384])
#define QKV16_D   25165824ull
#define WS_SLABS  25493504              // ushort region base: mfma-ready slabs
#define OFF_QH    0ull                  // [8][128w][128h][40c]
#define OFF_KH    5242880ull
#define OFF_QW    10485760ull           // [8][128h][128w][40c]
#define OFF_KW    15728640ull
#define OFF_VHU   20971520ull           // [8][128w][32c][136h]
#define OFF_VHD   25427968ull
#define OFF_VWU   29884416ull           // [8][128h][32c][136w]
#define OFF_VWD   34340864ull
#define WS_OH     44892160              // fp32 [8][128w][32c][128h] h-attn staging

typedef __attribute__((ext_vector_type(8))) short bf16x8;
typedef __attribute__((ext_vector_type(4))) float f32x4;

static __device__ __forceinline__ float bf2f(ushort u){ return __uint_as_float(((uint)u) << 16); }
static __device__ __forceinline__ ushort f2bf(float f){
  uint b = __float_as_uint(f);
  return (ushort)((b + 0x7fffu + ((b >> 16) & 1u)) >> 16);
}
static __device__ __forceinline__ bf16x8 ldfrag(const ushort* p){
  union { uint4 u; bf16x8 b; } cv; cv.u = *(const uint4*)p; return cv.b;
}

// ---------------- stats reduction: per-sample sum & sumsq ----------------
__global__ __launch_bounds__(256) void reduce_stats(const float* __restrict__ xu,
                                                    const float* __restrict__ xd,
                                                    float* __restrict__ ws) {
  int blk = blockIdx.x;                // 2*8*64
  int tensor = blk >> 9;
  int b = (blk >> 6) & 7;
  int chunk = blk & 63;
  const float* x = tensor ? xd : xu;
  const float4* p = (const float4*)(x + (size_t)b*NM + (size_t)chunk*(NM/64));
  float s = 0.f, sq = 0.f;
  for (int r = 0; r < 24; r++) {
    float4 v = p[threadIdx.x + r*256];
    s  += v.x + v.y + v.z + v.w;
    sq += v.x*v.x + v.y*v.y + v.z*v.z + v.w*v.w;
  }
  for (int o = 32; o; o >>= 1) { s += __shfl_down(s, o); sq += __shfl_down(sq, o); }
  __shared__ float ls[8];
  int wv = threadIdx.x >> 6, ln = threadIdx.x & 63;
  if (ln == 0) { ls[wv*2] = s; ls[wv*2+1] = sq; }
  __syncthreads();
  if (threadIdx.x == 0) {
    s  = ls[0] + ls[2] + ls[4] + ls[6];
    sq = ls[1] + ls[3] + ls[5] + ls[7];
    atomicAdd(&ws[WS_SUMS + (tensor*8 + b)*2],     s);
    atomicAdd(&ws[WS_SUMS + (tensor*8 + b)*2 + 1], sq);
  }
}

// ---------------- derived params ----------------
__global__ void compute_params(float* __restrict__ ws,
    const float* __restrict__ nwu, const float* __restrict__ nbu,
    const float* __restrict__ m1wu, const float* __restrict__ m1bu,
    const float* __restrict__ m2wu, const float* __restrict__ m2bu,
    const float* __restrict__ nwd, const float* __restrict__ nbd,
    const float* __restrict__ m1wd, const float* __restrict__ m1bd,
    const float* __restrict__ m2wd, const float* __restrict__ m2bd,
    const float* __restrict__ Wqu, const float* __restrict__ bqu,
    const float* __restrict__ Wqd, const float* __restrict__ bqd) {
  __shared__ float meanL[16], stdL[16];
  __shared__ float tuL[768], tdL[768];
  int t = threadIdx.x;
  if (t < 16) {
    float s = ws[WS_SUMS + t*2], sq = ws[WS_SUMS + t*2 + 1];
    const float inv = 1.f / (float)NM;
    float mean = s * inv;
    float var  = sq * inv - mean*mean;
    meanL[t] = mean;
    stdL[t]  = sqrtf(var + 1e-5f);
  }
  __syncthreads();
  for (int idx = t; idx < 768; idx += 256) {
    int b = idx / 96, c = idx % 96;
    float mu = meanL[b],   su = stdL[b];
    float md = meanL[8+b], sd = stdL[8+b];
    float scu = nwu[c] / su;
    float scd = nwd[c] / sd;
    float tcu = nbu[c] - mu*scu;
    float tcd = nbd[c] - md*scd;
    tuL[idx] = tcu; tdL[idx] = tcd;
    ws[WS_SU+idx] = scu; ws[WS_TU+idx] = tcu;
    ws[WS_SD+idx] = scd; ws[WS_TD+idx] = tcd;
    ws[WS_RU+idx] = su*m1wu[c] + m1bu[c];
    ws[WS_RD+idx] = sd*m1wd[c] + m1bd[c];
    ws[WS_CADD+idx] = (mu*m2wu[c] + m2bu[c]) + (md*m2wd[c] + m2bd[c]);
  }
  __syncthreads();
  for (int idx = t; idx < 3072; idx += 256) {
    int tensor = idx / 1536;
    int r = idx % 1536;
    int b = r / 192, o = r % 192;
    const float* Wq = tensor ? Wqd : Wqu;
    const float* tt = tensor ? tdL : tuL;
    float acc = tensor ? bqd[o] : bqu[o];
    for (int i = 0; i < 96; i++) acc += Wq[o*96 + i] * tt[b*96 + i];
    ws[(tensor ? WS_BPD : WS_BPU) + r] = acc;
  }
}

// ---------------- W' bf16 [tensor][b][192][104] (A-operand-ready) ----------------
__global__ __launch_bounds__(256) void compute_wprime(float* __restrict__ ws,
    const float* __restrict__ Wqu, const float* __restrict__ Wqd) {
  int idx = blockIdx.x*256 + threadIdx.x;   // 319488 total
  if (idx >= 319488) return;
  int tensor = idx / 159744;
  int r = idx % 159744;
  int b  = r / 19968;
  int r2 = r % 19968;
  int o  = r2 / 104, i = r2 % 104;
  ushort* wb = (ushort*)(ws + WS_WB16);
  ushort v = 0;
  if (i < 96) {
    const float* Wq = tensor ? Wqd : Wqu;
    const float* s  = ws + (tensor ? WS_SD : WS_SU);
    v = f2bf(Wq[o*96 + i] * s[b*96 + i]);
  }
  wb[idx] = v;
}

// ---------------- qkv GEMM via MFMA: C[192x16384] = W'[192x96] @ X[96x16384] ----------------
__global__ __launch_bounds__(256) void qkv_gemm(float* __restrict__ ws,
    const float* __restrict__ xu, const float* __restrict__ xd) {
  __shared__ __align__(16) ushort QL[33280];   // Al[192*104] + Bl[128*104] = 66560 B
  ushort* Al = QL;
  ushort* Bl = QL + 19968;
  int blk = blockIdx.x;                 // 2 tensor * 8 b * 128 ntile
  int tensor = blk >> 10;
  int rem = blk & 1023;
  int b = rem >> 7;
  int nt = rem & 127;
  int n0 = nt*128;
  const float* x = (tensor ? xd : xu) + (size_t)b*NM;
  const ushort* wb = (const ushort*)(ws + WS_WB16) + (size_t)(tensor*8 + b)*19968;
  const float* bp = ws + (tensor ? WS_BPD : WS_BPU) + b*192;
  ushort* outq16 = (ushort*)(ws + WS_QKV16) + (tensor ? QKV16_D : 0) + (size_t)b*NCO*NN;
  const int t = threadIdx.x;
  const int wv = t >> 6, lid = t & 63, l15 = lid & 15, l4 = lid >> 4;

  // stage A: linear copy; Al = 192*104 ushorts = 2496 uint4 (was 1248 -> V-half garbage bug)
  for (int it = 0; it < 10; it++) {
    int idx = t + it*256;
    if (idx < 2496) ((uint4*)Al)[idx] = ((const uint4*)wb)[idx];
  }
  // stage B: X^T bf16 [128][104]; tasks (i2 0..47, n4 0..31)
  for (int it = 0; it < 6; it++) {
    int idx = t + it*256;
    int i2 = (idx & 7) | ((idx >> 8) << 3);
    int n4 = (idx >> 3) & 31;
    const float* r0 = x + (size_t)(2*i2)*NN + n0 + n4*4;
    float4 a0 = *(const float4*)r0;
    float4 a1 = *(const float4*)(r0 + NN);
    uint p0 = (uint)f2bf(a0.x) | ((uint)f2bf(a1.x) << 16);
    uint p1 = (uint)f2bf(a0.y) | ((uint)f2bf(a1.y) << 16);
    uint p2 = (uint)f2bf(a0.z) | ((uint)f2bf(a1.z) << 16);
    uint p3 = (uint)f2bf(a0.w) | ((uint)f2bf(a1.w) << 16);
    ushort* base = &Bl[(size_t)(n4*4)*104 + 2*i2];
    *(uint*)(base)           = p0;
    *(uint*)(base + 104)     = p1;
    *(uint*)(base + 208)     = p2;
    *(uint*)(base + 312)     = p3;
  }
  __syncthreads();

  f32x4 z4 = {0.f,0.f,0.f,0.f};
  f32x4 acc[12][2];
  #pragma unroll
  for (int mt = 0; mt < 12; mt++) { acc[mt][0] = z4; acc[mt][1] = z4; }
  #pragma unroll
  for (int s = 0; s < 3; s++) {
    bf16x8 b0 = ldfrag(&Bl[((2*wv+0)*16 + l15)*104 + s*32 + l4*8]);
    bf16x8 b1 = ldfrag(&Bl[((2*wv+1)*16 + l15)*104 + s*32 + l4*8]);
    #pragma unroll
    for (int mt = 0; mt < 12; mt++) {
      bf16x8 a = ldfrag(&Al[(mt*16 + l15)*104 + s*32 + l4*8]);
      acc[mt][0] = __builtin_amdgcn_mfma_f32_16x16x32_bf16(a, b0, acc[mt][0], 0, 0, 0);
      acc[mt][1] = __builtin_amdgcn_mfma_f32_16x16x32_bf16(a, b1, acc[mt][1], 0, 0, 0);
    }
  }
  __syncthreads();       // all frag reads done; reuse QL as C bounce [192][128] u16
  ushort* Cl = QL;
  #pragma unroll
  for (int mt = 0; mt < 12; mt++) {
    #pragma unroll
    for (int r = 0; r < 4; r++) {
      int o = mt*16 + l4*4 + r;
      float bb = bp[o];
      Cl[o*128 + 32*wv + l15]      = f2bf(acc[mt][0][r] + bb);
      Cl[o*128 + 32*wv + 16 + l15] = f2bf(acc[mt][1][r] + bb);
    }
  }
  __syncthreads();
  // full tile store: 192 rows * 16 uint4-chunks = 3072 uint4
  for (int it = 0; it < 12; it++) {
    int idx = t + it*256;
    int o = idx >> 4, ch = idx & 15;
    *(uint4*)(outq16 + (size_t)o*NN + n0 + ch*8) = *(const uint4*)&Cl[o*128 + ch*8];
  }
}

// ---------------- prep: brick transpose qkv(bf16) -> mfma slabs ----------------
__global__ __launch_bounds__(256) void qkv_prep(float* __restrict__ ws) {
  __shared__ __align__(16) ushort Br[16*1320];   // [16c][33h][40w] c-stride 1320
  int bid = blockIdx.x;                           // 8 roles * 2cb * 8b * 4hb * 4wb = 2048
  int role = bid >> 8;
  int r = bid & 255;
  int cb = r >> 7, b = (r >> 4) & 7, hb = (r >> 2) & 3, wb = r & 3;
  const int chbt[8]  = {0,0,32,32,96,96,128,128};
  const int tenst[8] = {0,1,0,1,0,1,0,1};
  const int modet[8] = {0,0,1,1,2,2,3,3};
  const size_t dstofft[8] = {OFF_QH,OFF_KH,OFF_QW,OFF_KW,OFF_VHU,OFF_VHD,OFF_VWU,OFF_VWD};
  int mode = modet[role];
  const ushort* qkv16 = (const ushort*)(ws + WS_QKV16);
  const ushort* src = qkv16 + (tenst[role] ? QKV16_D : 0)
                    + (size_t)b*NCO*NN + (size_t)(chbt[role] + cb*16)*NN;
  ushort* dst = (ushort*)(ws + WS_SLABS) + dstofft[role];
  int t = threadIdx.x;
  for (int k = 0; k < 8; k++) {
    int idx = t + k*256;                          // 2048 = 16c*32h*4(w8)
    int c = idx >> 7, h = (idx >> 2) & 31, w8 = idx & 3;
    uint4 v = *(const uint4*)(src + (size_t)c*NN + (size_t)(hb*32 + h)*NWID + wb*32 + w8*8);
    *(uint4*)&Br[c*1320 + h*40 + w8*8] = v;
  }
  __syncthreads();
  if (mode <= 1) {
    for (int k = 0; k < 4; k++) {
      int idx = t + k*256;                        // 1024 = 32w*32h
      int p = idx >> 5, q = idx & 31;             // p=w, q=h
      uint uu[8];
      #pragma unroll
      for (int cc = 0; cc < 8; cc++) {
        ushort a0 = Br[(2*cc)*1320 + q*40 + p];
        ushort a1 = Br[(2*cc+1)*1320 + q*40 + p];
        uu[cc] = (uint)a0 | ((uint)a1 << 16);
      }
      size_t o = (mode == 0)
        ? ((size_t)(b*128 + wb*32 + p)*128 + hb*32 + q)*40
        : ((size_t)(b*128 + hb*32 + q)*128 + wb*32 + p)*40;
      *(uint4*)(dst + o + cb*16)     = make_uint4(uu[0],uu[1],uu[2],uu[3]);
      *(uint4*)(dst + o + cb*16 + 8) = make_uint4(uu[4],uu[5],uu[6],uu[7]);
    }
  } else if (mode == 2) {
    for (int k = 0; k < 2; k++) {
      int idx = t + k*256;                        // 512 = 32w*16c
      int w = idx >> 4, c = idx & 15;
      uint uu[16];
      #pragma unroll
      for (int hh = 0; hh < 16; hh++) {
        ushort a0 = Br[c*1320 + (2*hh)*40 + w];
        ushort a1 = Br[c*1320 + (2*hh+1)*40 + w];
        uu[hh] = (uint)a0 | ((uint)a1 << 16);
      }
      size_t o = ((size_t)(b*128 + wb*32 + w)*32 + cb*16 + c)*136 + hb*32;
      *(uint4*)(dst + o)      = make_uint4(uu[0],uu[1],uu[2],uu[3]);
      *(uint4*)(dst + o + 8)  = make_uint4(uu[4],uu[5],uu[6],uu[7]);
      *(uint4*)(dst + o + 16) = make_uint4(uu[8],uu[9],uu[10],uu[11]);
      *(uint4*)(dst + o + 24) = make_uint4(uu[12],uu[13],uu[14],uu[15]);
    }
  } else {
    for (int k = 0; k < 2; k++) {
      int idx = t + k*256;                        // 512 = 32h*16c
      int h = idx >> 4, c = idx & 15;
      size_t o = ((size_t)(b*128 + hb*32 + h)*32 + cb*16 + c)*136 + wb*32;
      const uint4* s = (const uint4*)&Br[c*1320 + h*40];
      *(uint4*)(dst + o)      = s[0];
      *(uint4*)(dst + o + 8)  = s[1];
      *(uint4*)(dst + o + 16) = s[2];
      *(uint4*)(dst + o + 24) = s[3];
    }
  }
}

// ---------------- MFMA spatial attention (AXIS 0 = h, 1 = w) ----------------
template<int AXIS>
__global__ __launch_bounds__(256) void attn_mfma(float* __restrict__ ws,
    const float* __restrict__ xu, const float* __restrict__ xd,
    float* __restrict__ out, const float* __restrict__ scale_p) {
  __shared__ __align__(16) ushort Qs[128*40];
  __shared__ __align__(16) ushort Ks[128*40];
  __shared__ __align__(16) ushort Vds[32*136];
  __shared__ __align__(16) ushort Vus[32*136];
  __shared__ __align__(16) ushort Pl[128*136];
  __shared__ float m1s[128], l1s[128];
  const int b = blockIdx.x >> 7, p2 = blockIdx.x & 127;
  const int t = threadIdx.x;
  const int wv = t >> 6, lid = t & 63, l15 = lid & 15, l4 = lid >> 4;
  const ushort* slab = (const ushort*)(ws + WS_SLABS);
  const ushort* qsrc  = slab + (AXIS ? OFF_QW : OFF_QH) + (size_t)(b*128 + p2)*5120;
  const ushort* ksrc  = slab + (AXIS ? OFF_KW : OFF_KH) + (size_t)(b*128 + p2)*5120;
  const ushort* vdsrc = slab + (AXIS ? OFF_VWD : OFF_VHD) + (size_t)(b*128 + p2)*4352;
  const ushort* vusrc = slab + (AXIS ? OFF_VWU : OFF_VHU) + (size_t)(b*128 + p2)*4352;
  for (int i = t; i < 2368; i += 256) {
    const uint4* s; uint4* d;
    if (i < 640)       { s = (const uint4*)qsrc + i;          d = (uint4*)Qs + i; }
    else if (i < 1280) { s = (const uint4*)ksrc + (i-640);    d = (uint4*)Ks + (i-640); }
    else if (i < 1824) { s = (const uint4*)vdsrc + (i-1280);  d = (uint4*)Vds + (i-1280); }
    else               { s = (const uint4*)vusrc + (i-1824);  d = (uint4*)Vus + (i-1824); }
    *d = *s;
  }
  const float sc = scale_p[0];
  const int cbas = AXIS ? 32 : 0;
  float ruv0 = ws[WS_RU + b*96 + cbas + l15];
  float ruv1 = ws[WS_RU + b*96 + cbas + 16 + l15];
  float rdv0 = ws[WS_RD + b*96 + cbas + l15];
  float rdv1 = ws[WS_RD + b*96 + cbas + 16 + l15];
  __syncthreads();

  f32x4 z4 = {0.f,0.f,0.f,0.f};
  f32x4 s1[2][8];
  // ---- S1[i][j] = sum_c Q[i][c] K[j][c], wave owns i-tiles {2wv,2wv+1} ----
  {
    bf16x8 bfr[8];
    #pragma unroll
    for (int tj = 0; tj < 8; tj++) bfr[tj] = ldfrag(&Ks[(tj*16 + l15)*40 + l4*8]);
    #pragma unroll
    for (int ti = 0; ti < 2; ti++) {
      bf16x8 a = ldfrag(&Qs[((2*wv+ti)*16 + l15)*40 + l4*8]);
      #pragma unroll
      for (int tj = 0; tj < 8; tj++)
        s1[ti][tj] = __builtin_amdgcn_mfma_f32_16x16x32_bf16(a, bfr[tj], z4, 0, 0, 0);
    }
  }
  // ---- row softmax over j; write P1 bf16 ----
  #pragma unroll
  for (int ti = 0; ti < 2; ti++) {
    #pragma unroll
    for (int r = 0; r < 4; r++) {
      float mx = -3.0e38f;
      #pragma unroll
      for (int tj = 0; tj < 8; tj++) { float v = s1[ti][tj][r]*sc; s1[ti][tj][r] = v; mx = fmaxf(mx, v); }
      mx = fmaxf(mx, __shfl_xor(mx, 1)); mx = fmaxf(mx, __shfl_xor(mx, 2));
      mx = fmaxf(mx, __shfl_xor(mx, 4)); mx = fmaxf(mx, __shfl_xor(mx, 8));
      float sm = 0.f;
      #pragma unroll
      for (int tj = 0; tj < 8; tj++) { float e = __expf(s1[ti][tj][r] - mx); s1[ti][tj][r] = e; sm += e; }
      sm += __shfl_xor(sm, 1); sm += __shfl_xor(sm, 2); sm += __shfl_xor(sm, 4); sm += __shfl_xor(sm, 8);
      int row = 32*wv + ti*16 + l4*4 + r;
      if (l15 == 0) { m1s[row] = mx; l1s[row] = sm; }
      float inv = __fdividef(1.f, sm);
      #pragma unroll
      for (int tj = 0; tj < 8; tj++) Pl[row*136 + tj*16 + l15] = f2bf(s1[ti][tj][r]*inv);
    }
  }
  __syncthreads();
  // ---- PV1: o1[i][c] = sum_j P1[i][j] Vd[c][j] ----
  f32x4 o1[2][2] = {{z4,z4},{z4,z4}};
  #pragma unroll
  for (int ks = 0; ks < 4; ks++) {
    bf16x8 bv0 = ldfrag(&Vds[l15*136 + ks*32 + l4*8]);
    bf16x8 bv1 = ldfrag(&Vds[(16 + l15)*136 + ks*32 + l4*8]);
    #pragma unroll
    for (int mt = 0; mt < 2; mt++) {
      bf16x8 a = ldfrag(&Pl[((2*wv+mt)*16 + l15)*136 + ks*32 + l4*8]);
      o1[mt][0] = __builtin_amdgcn_mfma_f32_16x16x32_bf16(a, bv0, o1[mt][0], 0, 0, 0);
      o1[mt][1] = __builtin_amdgcn_mfma_f32_16x16x32_bf16(a, bv1, o1[mt][1], 0, 0, 0);
    }
  }
  // ---- S2[j][i] = S1^T via mfma(K, Q) ----
  {
    bf16x8 bq[8];
    #pragma unroll
    for (int it = 0; it < 8; it++) bq[it] = ldfrag(&Qs[(it*16 + l15)*40 + l4*8]);
    #pragma unroll
    for (int tjt = 0; tjt < 2; tjt++) {
      bf16x8 a = ldfrag(&Ks[((2*wv+tjt)*16 + l15)*40 + l4*8]);
      #pragma unroll
      for (int it = 0; it < 8; it++)
        s1[tjt][it] = __builtin_amdgcn_mfma_f32_16x16x32_bf16(a, bq[it], z4, 0, 0, 0);
    }
  }
  // ---- pass-2 softmax ----
  if (AXIS == 1) {
    #pragma unroll
    for (int tjt = 0; tjt < 2; tjt++) {
      #pragma unroll
      for (int r = 0; r < 4; r++) {
        float mx = -3.0e38f;
        #pragma unroll
        for (int it = 0; it < 8; it++) { float v = s1[tjt][it][r]*sc; s1[tjt][it][r] = v; mx = fmaxf(mx, v); }
        mx = fmaxf(mx, __shfl_xor(mx, 1)); mx = fmaxf(mx, __shfl_xor(mx, 2));
        mx = fmaxf(mx, __shfl_xor(mx, 4)); mx = fmaxf(mx, __shfl_xor(mx, 8));
        float sm = 0.f;
        #pragma unroll
        for (int it = 0; it < 8; it++) { float e = __expf(s1[tjt][it][r] - mx); s1[tjt][it][r] = e; sm += e; }
        sm += __shfl_xor(sm, 1); sm += __shfl_xor(sm, 2); sm += __shfl_xor(sm, 4); sm += __shfl_xor(sm, 8);
        float inv = __fdividef(1.f, sm);
        #pragma unroll
        for (int it = 0; it < 8; it++) s1[tjt][it][r] *= inv;
      }
    }
  } else {
    float mi[8], li[8];
    #pragma unroll
    for (int it = 0; it < 8; it++) {
      mi[it] = m1s[it*16 + l15];
      li[it] = __fdividef(1.f, l1s[it*16 + l15]);
    }
    #pragma unroll
    for (int tjt = 0; tjt < 2; tjt++)
      #pragma unroll
      for (int it = 0; it < 8; it++)
        #pragma unroll
        for (int r = 0; r < 4; r++)
          s1[tjt][it][r] = __expf(s1[tjt][it][r]*sc - mi[it]) * li[it];
  }
  __syncthreads();   // all PV1 reads of Pl done
  #pragma unroll
  for (int tjt = 0; tjt < 2; tjt++)
    #pragma unroll
    for (int r = 0; r < 4; r++) {
      int row = 32*wv + tjt*16 + l4*4 + r;
      #pragma unroll
      for (int it = 0; it < 8; it++) Pl[row*136 + it*16 + l15] = f2bf(s1[tjt][it][r]);
    }
  __syncthreads();
  // ---- PV2: o2[j][c] = sum_i P2[j][i] Vu[c][i] ----
  f32x4 o2[2][2] = {{z4,z4},{z4,z4}};
  #pragma unroll
  for (int ks = 0; ks < 4; ks++) {
    bf16x8 bv0 = ldfrag(&Vus[l15*136 + ks*32 + l4*8]);
    bf16x8 bv1 = ldfrag(&Vus[(16 + l15)*136 + ks*32 + l4*8]);
    #pragma unroll
    for (int mt = 0; mt < 2; mt++) {
      bf16x8 a = ldfrag(&Pl[((2*wv+mt)*16 + l15)*136 + ks*32 + l4*8]);
      o2[mt][0] = __builtin_amdgcn_mfma_f32_16x16x32_bf16(a, bv0, o2[mt][0], 0, 0, 0);
      o2[mt][1] = __builtin_amdgcn_mfma_f32_16x16x32_bf16(a, bv1, o2[mt][1], 0, 0, 0);
    }
  }
  __syncthreads();   // PV2 reads done; reuse Pl as fp32 stage [32][132]
  float* St = (float*)Pl;
  #pragma unroll
  for (int mt = 0; mt < 2; mt++)
    #pragma unroll
    for (int nt = 0; nt < 2; nt++) {
      float ru = nt ? ruv1 : ruv0;
      float rd = nt ? rdv1 : rdv0;
      float4 vv;
      vv.x = o1[mt][nt][0]*ru + o2[mt][nt][0]*rd;
      vv.y = o1[mt][nt][1]*ru + o2[mt][nt][1]*rd;
      vv.z = o1[mt][nt][2]*ru + o2[mt][nt][2]*rd;
      vv.w = o1[mt][nt][3]*ru + o2[mt][nt][3]*rd;
      *(float4*)&St[(nt*16 + l15)*132 + (2*wv+mt)*16 + l4*4] = vv;
    }
  __syncthreads();
  if (AXIS == 1) {
    for (int k = 0; k < 4; k++) {
      int idx = t + k*256;
      int c = idx >> 5, p4 = idx & 31;
      float4 v = *(const float4*)&St[c*132 + p4*4];
      float ca = ws[WS_CADD + b*96 + 32 + c];
      size_t off = ((size_t)(b*NC + 32 + c)*NH + p2)*NWID + p4*4;
      float4 a = *(const float4*)(xu + off);
      float4 dd = *(const float4*)(xd + off);
      v.x += ca + a.x + dd.x; v.y += ca + a.y + dd.y;
      v.z += ca + a.z + dd.z; v.w += ca + a.w + dd.w;
      *(float4*)(out + off) = v;
    }
  } else {
    float* oh = ws + WS_OH;
    for (int k = 0; k < 4; k++) {
      int idx = t + k*256;
      int c = idx >> 5, p4 = idx & 31;
      float4 v = *(const float4*)&St[c*132 + p4*4];
      *(float4*)(oh + ((size_t)(b*128 + p2)*32 + c)*128 + p4*4) = v;
    }
  }
}

// ---------------- merge h-attn staging into final out (ch 0..31) ----------------
__global__ __launch_bounds__(256) void merge_h(float* __restrict__ ws,
    const float* __restrict__ xu, const float* __restrict__ xd,
    float* __restrict__ out) {
  __shared__ float T[32][33];
  int bid = blockIdx.x;                 // 8b*32c*4ht*4wt = 4096
  int b = bid >> 9, c = (bid >> 4) & 31, ht = (bid >> 2) & 3, wt = bid & 3;
  int t = threadIdx.x;
  const float* oh = ws + WS_OH;
  {
    int w = t >> 3, h4 = t & 7;
    float4 v = *(const float4*)(oh + ((size_t)(b*128 + wt*32 + w)*32 + c)*128 + ht*32 + h4*4);
    T[w][h4*4+0] = v.x; T[w][h4*4+1] = v.y; T[w][h4*4+2] = v.z; T[w][h4*4+3] = v.w;
  }
  __syncthreads();
  {
    int h = t >> 3, w4 = t & 7;
    float ca = ws[WS_CADD + b*96 + c];
    size_t off = ((size_t)(b*NC + c)*NH + ht*32 + h)*NWID + wt*32 + w4*4;
    float4 a = *(const float4*)(xu + off);
    float4 d = *(const float4*)(xd + off);
    float4 v;
    v.x = T[w4*4+0][h] + ca + a.x + d.x;
    v.y = T[w4*4+1][h] + ca + a.y + d.y;
    v.z = T[w4*4+2][h] + ca + a.z + d.z;
    v.w = T[w4*4+3][h] + ca + a.w + d.w;
    *(float4*)(out + off) = v;
  }
}

// ---------------- channel attention: score accumulation (bf16 in) ----------------
__global__ __launch_bounds__(256) void attn_c1(float* __restrict__ ws) {
  __shared__ float qs[32][260], ks[32][260];
  int b = blockIdx.x >> 6, chunk = blockIdx.x & 63;
  int n0 = chunk * 256;
  int t = threadIdx.x;
  const ushort* qkv16 = (const ushort*)(ws + WS_QKV16);
  const ushort* qp = qkv16 + ((size_t)b*NCO + 64)*NN + n0;
  const ushort* kp = qkv16 + QKV16_D + ((size_t)b*NCO + 64)*NN + n0;
  for (int r = 0; r < 4; r++) {
    int idx = t + r*256;
    int c = idx >> 5, n8 = idx & 31;
    uint4 v = *(const uint4*)(qp + (size_t)c*NN + n8*8);
    uint4 w = *(const uint4*)(kp + (size_t)c*NN + n8*8);
    float* q = &qs[c][n8*8];
    float* kk = &ks[c][n8*8];
    q[0] = bf2f((ushort)(v.x & 0xffff)); q[1] = bf2f((ushort)(v.x >> 16));
    q[2] = bf2f((ushort)(v.y & 0xffff)); q[3] = bf2f((ushort)(v.y >> 16));
    q[4] = bf2f((ushort)(v.z & 0xffff)); q[5] = bf2f((ushort)(v.z >> 16));
    q[6] = bf2f((ushort)(v.w & 0xffff)); q[7] = bf2f((ushort)(v.w >> 16));
    kk[0] = bf2f((ushort)(w.x & 0xffff)); kk[1] = bf2f((ushort)(w.x >> 16));
    kk[2] = bf2f((ushort)(w.y & 0xffff)); kk[3] = bf2f((ushort)(w.y >> 16));
    kk[4] = bf2f((ushort)(w.z & 0xffff)); kk[5] = bf2f((ushort)(w.z >> 16));
    kk[6] = bf2f((ushort)(w.w & 0xffff)); kk[7] = bf2f((ushort)(w.w >> 16));
  }
  __syncthreads();
  int d = t & 31, cbq = t >> 5;
  float a[4] = {0.f,0.f,0.f,0.f};
  for (int n4 = 0; n4 < 64; n4++) {
    float4 kv = *(const float4*)&ks[d][n4*4];
    #pragma unroll
    for (int r = 0; r < 4; r++) {
      float4 qv = *(const float4*)&qs[cbq + 8*r][n4*4];
      a[r] += qv.x*kv.x + qv.y*kv.y + qv.z*kv.z + qv.w*kv.w;
    }
  }
  #pragma unroll
  for (int r = 0; r < 4; r++)
    atomicAdd(&ws[WS_SC + b*1024 + (cbq + 8*r)*32 + d], a[r]);
}

// ---------------- channel attention: softmax ----------------
__global__ void attn_c2(float* __restrict__ ws, const float* __restrict__ scale_p) {
  int b = blockIdx.x, c = threadIdx.x;
  if (c >= 32) return;
  float sc = scale_p[0];
  float row[32];
  float m = -3.0e38f;
  for (int d = 0; d < 32; d++) { row[d] = ws[WS_SC + b*1024 + c*32 + d] * sc; m = fmaxf(m, row[d]); }
  float s = 0.f;
  for (int d = 0; d < 32; d++) { row[d] = __expf(row[d] - m); s += row[d]; }
  float inv = 1.f / s;
  for (int d = 0; d < 32; d++) ws[WS_AC + b*1024 + c*32 + d] = row[d]*inv;
}

// ---------------- channel attention: apply + epilogue (ch 64..95) ----------------
__global__ __launch_bounds__(256) void attn_c3(float* __restrict__ ws,
    const float* __restrict__ xu, const float* __restrict__ xd,
    float* __restrict__ out) {
  __shared__ float AsT[32][36];
  __shared__ float ruL[32], rdL[32], caL[32];
  int b = blockIdx.x >> 6, chunk = blockIdx.x & 63;
  int t = threadIdx.x;
  for (int r = 0; r < 4; r++) {
    int idx = t + r*256;
    int c = idx >> 5, d = idx & 31;
    AsT[d][c] = ws[WS_AC + b*1024 + idx];
  }
  if (t < 32) {
    ruL[t] = ws[WS_RU + b*96 + 64 + t];
    rdL[t] = ws[WS_RD + b*96 + 64 + t];
    caL[t] = ws[WS_CADD + b*96 + 64 + t];
  }
  __syncthreads();
  int n = chunk*256 + t;
  const ushort* qkv16 = (const ushort*)(ws + WS_QKV16);
  const ushort* vdp = qkv16 + QKV16_D + ((size_t)b*NCO + 160)*NN + n;
  const ushort* vup = qkv16 + ((size_t)b*NCO + 160)*NN + n;
  float acc1[32], acc2[32];
  #pragma unroll
  for (int c2 = 0; c2 < 32; c2++) { acc1[c2]=0.f; acc2[c2]=0.f; }
  for (int d = 0; d < 32; d++) {
    float vd = bf2f(vdp[(size_t)d*NN]);
    float vu = bf2f(vup[(size_t)d*NN]);
    #pragma unroll
    for (int c4 = 0; c4 < 8; c4++) {
      float4 av = *(const float4*)&AsT[d][c4*4];
      acc1[c4*4+0] += av.x*vd; acc2[c4*4+0] += av.x*vu;
      acc1[c4*4+1] += av.y*vd; acc2[c4*4+1] += av.y*vu;
      acc1[c4*4+2] += av.z*vd; acc2[c4*4+2] += av.z*vu;
      acc1[c4*4+3] += av.w*vd; acc2[c4*4+3] += av.w*vu;
    }
  }
  size_t base = ((size_t)(b*NC) + 64)*NN + n;
  #pragma unroll
  for (int c2 = 0; c2 < 32; c2++) {
    size_t off = base + (size_t)c2*NN;
    out[off] = acc1[c2]*ruL[c2] + acc2[c2]*rdL[c2] + caL[c2] + xu[off] + xd[off];
  }
}

extern "C" void kernel_launch(void* const* d_in, const int* in_sizes, int n_in,
                              void* d_out, int out_size, void* d_ws, size_t ws_size,
                              hipStream_t stream) {
  (void)in_sizes; (void)n_in; (void)out_size; (void)ws_size;
  const float* xu   = (const float*)d_in[0];
  const float* xd   = (const float*)d_in[1];
  const float* nwu  = (const float*)d_in[2];
  const float* nbu  = (const float*)d_in[3];
  const float* m1wu = (const float*)d_in[4];
  const float* m1bu = (const float*)d_in[5];
  const float* m2wu = (const float*)d_in[6];
  const float* m2bu = (const float*)d_in[7];
  const float* nwd  = (const float*)d_in[8];
  const float* nbd  = (const float*)d_in[9];
  const float* m1wd = (const float*)d_in[10];
  const float* m1bd = (const float*)d_in[11];
  const float* m2wd = (const float*)d_in[12];
  const float* m2bd = (const float*)d_in[13];
  const float* Wqu  = (const float*)d_in[14];
  const float* bqu  = (const float*)d_in[15];
  const float* Wqd  = (const float*)d_in[16];
  const float* bqd  = (const float*)d_in[17];
  const float* sch  = (const float*)d_in[18];
  const float* scw  = (const float*)d_in[19];
  const float* scc  = (const float*)d_in[20];
  float* ws  = (float*)d_ws;
  float* out = (float*)d_out;

  hipMemsetAsync(d_ws, 0, 8224*sizeof(float), stream);
  reduce_stats<<<1024, 256, 0, stream>>>(xu, xd, ws);
  compute_params<<<1, 256, 0, stream>>>(ws, nwu, nbu, m1wu, m1bu, m2wu, m2bu,
                                        nwd, nbd, m1wd, m1bd, m2wd, m2bd,
                                        Wqu, bqu, Wqd, bqd);
  compute_wprime<<<1248, 256, 0, stream>>>(ws, Wqu, Wqd);
  qkv_gemm<<<2048, 256, 0, stream>>>(ws, xu, xd);
  qkv_prep<<<2048, 256, 0, stream>>>(ws);
  attn_mfma<0><<<1024, 256, 0, stream>>>(ws, xu, xd, out, sch);
  attn_mfma<1><<<1024, 256, 0, stream>>>(ws, xu, xd, out, scw);
  merge_h<<<4096, 256, 0, stream>>>(ws, xu, xd, out);
  attn_c1<<<512, 256, 0, stream>>>(ws);
  attn_c2<<<8, 64, 0, stream>>>(ws, scc);
  attn_c3<<<512, 256, 0, stream>>>(ws, xu, xd, out);
}

// Round 6
// 256.748 us; speedup vs baseline: 3.4200x; 1.1402x over previous
//
#include <hip/hip_runtime.h>
#include <math.h>

#define NB 8
#define NC 96
#define NH 128
#define NWID 128
#define NN (NH*NWID)      // 16384
#define NCO 192
#define NM (NC*NN)        // 1572864

// ---------------- workspace layout (float offsets) ----------------
#define WS_SUMS   0                     // [2][8][2]  (zeroed)
#define WS_SC     32                    // [8][32][32] (zeroed)
#define WS_AC     8224                  // [8][32][32]
#define WS_SU     16416                 // [8][96]
#define WS_TU     17184
#define WS_SD     17952
#define WS_TD     18720
#define WS_RU     19488                 // resc_u [8][96]
#define WS_RD     20256                 // resc_d
#define WS_CADD   21024                 // rebias_u+rebias_d
#define WS_BPU    21792                 // eff bias [8][192]
#define WS_BPD    23328
#define WS_WB16   24864                 // bf16 W' [2][8][192][104] (ushort region, 319488 u16)
#define WS_QKV16  327680                // ushort region: 2 tensors x 25165824 u16 (bf16 qkv [b][192][16384]; only ch 64..127,160..191 valid)
#define QKV16_D   25165824ull
#define WS_SLABS  25493504              // ushort region base: mfma-ready slabs
#define OFF_QH    0ull                  // [8][128w][128h][40c]
#define OFF_KH    5242880ull
#define OFF_QW    10485760ull           // [8][128h][128w][40c]
#define OFF_KW    15728640ull
#define OFF_VHU   20971520ull           // [8][128w][32c][136h]
#define OFF_VHD   25427968ull
#define OFF_VWU   29884416ull           // [8][128h][32c][136w]
#define OFF_VWD   34340864ull
#define WS_OH     44892160              // fp32 [8][128w][32c][128h] h-attn staging

typedef __attribute__((ext_vector_type(8))) short bf16x8;
typedef __attribute__((ext_vector_type(4))) float f32x4;

static __device__ __forceinline__ float bf2f(ushort u){ return __uint_as_float(((uint)u) << 16); }
static __device__ __forceinline__ ushort f2bf(float f){
  uint b = __float_as_uint(f);
  return (ushort)((b + 0x7fffu + ((b >> 16) & 1u)) >> 16);
}
static __device__ __forceinline__ bf16x8 ldfrag(const ushort* p){
  union { uint4 u; bf16x8 b; } cv; cv.u = *(const uint4*)p; return cv.b;
}

// ---------------- stats reduction: per-sample sum & sumsq ----------------
__global__ __launch_bounds__(256) void reduce_stats(const float* __restrict__ xu,
                                                    const float* __restrict__ xd,
                                                    float* __restrict__ ws) {
  int blk = blockIdx.x;                // 2*8*64
  int tensor = blk >> 9;
  int b = (blk >> 6) & 7;
  int chunk = blk & 63;
  const float* x = tensor ? xd : xu;
  const float4* p = (const float4*)(x + (size_t)b*NM + (size_t)chunk*(NM/64));
  float s = 0.f, sq = 0.f;
  for (int r = 0; r < 24; r++) {
    float4 v = p[threadIdx.x + r*256];
    s  += v.x + v.y + v.z + v.w;
    sq += v.x*v.x + v.y*v.y + v.z*v.z + v.w*v.w;
  }
  for (int o = 32; o; o >>= 1) { s += __shfl_down(s, o); sq += __shfl_down(sq, o); }
  __shared__ float ls[8];
  int wv = threadIdx.x >> 6, ln = threadIdx.x & 63;
  if (ln == 0) { ls[wv*2] = s; ls[wv*2+1] = sq; }
  __syncthreads();
  if (threadIdx.x == 0) {
    s  = ls[0] + ls[2] + ls[4] + ls[6];
    sq = ls[1] + ls[3] + ls[5] + ls[7];
    atomicAdd(&ws[WS_SUMS + (tensor*8 + b)*2],     s);
    atomicAdd(&ws[WS_SUMS + (tensor*8 + b)*2 + 1], sq);
  }
}

// ---------------- derived params ----------------
__global__ void compute_params(float* __restrict__ ws,
    const float* __restrict__ nwu, const float* __restrict__ nbu,
    const float* __restrict__ m1wu, const float* __restrict__ m1bu,
    const float* __restrict__ m2wu, const float* __restrict__ m2bu,
    const float* __restrict__ nwd, const float* __restrict__ nbd,
    const float* __restrict__ m1wd, const float* __restrict__ m1bd,
    const float* __restrict__ m2wd, const float* __restrict__ m2bd,
    const float* __restrict__ Wqu, const float* __restrict__ bqu,
    const float* __restrict__ Wqd, const float* __restrict__ bqd) {
  __shared__ float meanL[16], stdL[16];
  __shared__ float tuL[768], tdL[768];
  int t = threadIdx.x;
  if (t < 16) {
    float s = ws[WS_SUMS + t*2], sq = ws[WS_SUMS + t*2 + 1];
    const float inv = 1.f / (float)NM;
    float mean = s * inv;
    float var  = sq * inv - mean*mean;
    meanL[t] = mean;
    stdL[t]  = sqrtf(var + 1e-5f);
  }
  __syncthreads();
  for (int idx = t; idx < 768; idx += 256) {
    int b = idx / 96, c = idx % 96;
    float mu = meanL[b],   su = stdL[b];
    float md = meanL[8+b], sd = stdL[8+b];
    float scu = nwu[c] / su;
    float scd = nwd[c] / sd;
    float tcu = nbu[c] - mu*scu;
    float tcd = nbd[c] - md*scd;
    tuL[idx] = tcu; tdL[idx] = tcd;
    ws[WS_SU+idx] = scu; ws[WS_TU+idx] = tcu;
    ws[WS_SD+idx] = scd; ws[WS_TD+idx] = tcd;
    ws[WS_RU+idx] = su*m1wu[c] + m1bu[c];
    ws[WS_RD+idx] = sd*m1wd[c] + m1bd[c];
    ws[WS_CADD+idx] = (mu*m2wu[c] + m2bu[c]) + (md*m2wd[c] + m2bd[c]);
  }
  __syncthreads();
  for (int idx = t; idx < 3072; idx += 256) {
    int tensor = idx / 1536;
    int r = idx % 1536;
    int b = r / 192, o = r % 192;
    const float* Wq = tensor ? Wqd : Wqu;
    const float* tt = tensor ? tdL : tuL;
    float acc = tensor ? bqd[o] : bqu[o];
    for (int i = 0; i < 96; i++) acc += Wq[o*96 + i] * tt[b*96 + i];
    ws[(tensor ? WS_BPD : WS_BPU) + r] = acc;
  }
}

// ---------------- W' bf16 [tensor][b][192][104] (A-operand-ready) ----------------
__global__ __launch_bounds__(256) void compute_wprime(float* __restrict__ ws,
    const float* __restrict__ Wqu, const float* __restrict__ Wqd) {
  int idx = blockIdx.x*256 + threadIdx.x;   // 319488 total
  if (idx >= 319488) return;
  int tensor = idx / 159744;
  int r = idx % 159744;
  int b  = r / 19968;
  int r2 = r % 19968;
  int o  = r2 / 104, i = r2 % 104;
  ushort* wb = (ushort*)(ws + WS_WB16);
  ushort v = 0;
  if (i < 96) {
    const float* Wq = tensor ? Wqd : Wqu;
    const float* s  = ws + (tensor ? WS_SD : WS_SU);
    v = f2bf(Wq[o*96 + i] * s[b*96 + i]);
  }
  wb[idx] = v;
}

// ---------------- qkv GEMM via MFMA + fused slab epilogue ----------------
// block (tensor, b, h=nt): C[192][128w] tile = one full (b,h) row.
// Epilogue writes: qkv16 ch {64..127,160..191}; QH/KH [b][w][h][40c];
// QW/KW [b][h][w][40c]; VWU/VWD [b][h][32c][136w].
__global__ __launch_bounds__(256) void qkv_gemm(float* __restrict__ ws,
    const float* __restrict__ xu, const float* __restrict__ xd) {
  __shared__ __align__(16) ushort QL[33280];   // Al[192*104] + Bl[128*104] = 66560 B
  ushort* Al = QL;
  ushort* Bl = QL + 19968;
  int blk = blockIdx.x;                 // 2 tensor * 8 b * 128 h
  int tensor = blk >> 10;
  int rem = blk & 1023;
  int b = rem >> 7;
  int nt = rem & 127;                   // = h
  int n0 = nt*128;
  const float* x = (tensor ? xd : xu) + (size_t)b*NM;
  const ushort* wb = (const ushort*)(ws + WS_WB16) + (size_t)(tensor*8 + b)*19968;
  const float* bp = ws + (tensor ? WS_BPD : WS_BPU) + b*192;
  ushort* outq16 = (ushort*)(ws + WS_QKV16) + (tensor ? QKV16_D : 0) + (size_t)b*NCO*NN;
  ushort* slab = (ushort*)(ws + WS_SLABS);
  const int t = threadIdx.x;
  const int wv = t >> 6, lid = t & 63, l15 = lid & 15, l4 = lid >> 4;

  // stage A: linear copy; Al = 192*104 ushorts = 2496 uint4
  for (int it = 0; it < 10; it++) {
    int idx = t + it*256;
    if (idx < 2496) ((uint4*)Al)[idx] = ((const uint4*)wb)[idx];
  }
  // stage B: X^T bf16 [128][104]; tasks (i2 0..47, n4 0..31)
  for (int it = 0; it < 6; it++) {
    int idx = t + it*256;
    int i2 = (idx & 7) | ((idx >> 8) << 3);
    int n4 = (idx >> 3) & 31;
    const float* r0 = x + (size_t)(2*i2)*NN + n0 + n4*4;
    float4 a0 = *(const float4*)r0;
    float4 a1 = *(const float4*)(r0 + NN);
    uint p0 = (uint)f2bf(a0.x) | ((uint)f2bf(a1.x) << 16);
    uint p1 = (uint)f2bf(a0.y) | ((uint)f2bf(a1.y) << 16);
    uint p2 = (uint)f2bf(a0.z) | ((uint)f2bf(a1.z) << 16);
    uint p3 = (uint)f2bf(a0.w) | ((uint)f2bf(a1.w) << 16);
    ushort* base = &Bl[(size_t)(n4*4)*104 + 2*i2];
    *(uint*)(base)           = p0;
    *(uint*)(base + 104)     = p1;
    *(uint*)(base + 208)     = p2;
    *(uint*)(base + 312)     = p3;
  }
  __syncthreads();

  f32x4 z4 = {0.f,0.f,0.f,0.f};
  f32x4 acc[12][2];
  #pragma unroll
  for (int mt = 0; mt < 12; mt++) { acc[mt][0] = z4; acc[mt][1] = z4; }
  #pragma unroll
  for (int s = 0; s < 3; s++) {
    bf16x8 b0 = ldfrag(&Bl[((2*wv+0)*16 + l15)*104 + s*32 + l4*8]);
    bf16x8 b1 = ldfrag(&Bl[((2*wv+1)*16 + l15)*104 + s*32 + l4*8]);
    #pragma unroll
    for (int mt = 0; mt < 12; mt++) {
      bf16x8 a = ldfrag(&Al[(mt*16 + l15)*104 + s*32 + l4*8]);
      acc[mt][0] = __builtin_amdgcn_mfma_f32_16x16x32_bf16(a, b0, acc[mt][0], 0, 0, 0);
      acc[mt][1] = __builtin_amdgcn_mfma_f32_16x16x32_bf16(a, b1, acc[mt][1], 0, 0, 0);
    }
  }
  __syncthreads();       // all frag reads done; reuse QL as C bounce [192][128] u16
  ushort* Cl = QL;
  #pragma unroll
  for (int mt = 0; mt < 12; mt++) {
    #pragma unroll
    for (int r = 0; r < 4; r++) {
      int o = mt*16 + l4*4 + r;
      float bb = bp[o];
      Cl[o*128 + 32*wv + l15]      = f2bf(acc[mt][0][r] + bb);
      Cl[o*128 + 32*wv + 16 + l15] = f2bf(acc[mt][1][r] + bb);
    }
  }
  __syncthreads();
  // (1) qkv16 store, 96 channels {64..127, 160..191}: 1536 uint4
  for (int it = 0; it < 6; it++) {
    int idx = t + it*256;
    int lr = idx >> 4, ch = idx & 15;
    int o = (lr < 64) ? (64 + lr) : (96 + lr);
    *(uint4*)(outq16 + (size_t)o*NN + n0 + ch*8) = *(const uint4*)&Cl[o*128 + ch*8];
  }
  // (2) Q/K h- and w-slabs: 256 tasks (axis 0: ch 0..31 -> *H; axis 1: ch 32..63 -> *W)
  {
    int axis = t >> 7, w = t & 127;
    ushort* dstq = slab + (tensor ? (axis ? OFF_KW : OFF_KH) : (axis ? OFF_QW : OFF_QH));
    size_t o = axis ? ((size_t)(b*128 + nt)*128 + w)*40
                    : ((size_t)(b*128 + w)*128 + nt)*40;
    uint uu[16];
    #pragma unroll
    for (int k = 0; k < 16; k++) {
      ushort a0 = Cl[(axis*32 + 2*k)*128 + w];
      ushort a1 = Cl[(axis*32 + 2*k + 1)*128 + w];
      uu[k] = (uint)a0 | ((uint)a1 << 16);
    }
    *(uint4*)(dstq + o)      = make_uint4(uu[0],uu[1],uu[2],uu[3]);
    *(uint4*)(dstq + o + 8)  = make_uint4(uu[4],uu[5],uu[6],uu[7]);
    *(uint4*)(dstq + o + 16) = make_uint4(uu[8],uu[9],uu[10],uu[11]);
    *(uint4*)(dstq + o + 24) = make_uint4(uu[12],uu[13],uu[14],uu[15]);
  }
  // (3) VW slab (ch 128..159): 512 uint4 tasks
  {
    ushort* dstv = slab + (tensor ? OFF_VWD : OFF_VWU);
    for (int k = 0; k < 2; k++) {
      int idx = t + k*256;
      int c = idx >> 4, ch = idx & 15;
      *(uint4*)(dstv + ((size_t)(b*128 + nt)*32 + c)*136 + ch*8) =
          *(const uint4*)&Cl[(128 + c)*128 + ch*8];
    }
  }
}

// ---------------- prep: VH slabs only (ch 96..127 -> [b][w][32c][136h]) ----------------
__global__ __launch_bounds__(256) void qkv_prep(float* __restrict__ ws) {
  __shared__ __align__(16) ushort Br[16*1320];   // [16c][33h][40w] c-stride 1320
  int bid = blockIdx.x;                           // 2 tensor * 2cb * 8b * 4hb * 4wb = 512
  int tensor = bid >> 8;
  int r = bid & 255;
  int cb = r >> 7, b = (r >> 4) & 7, hb = (r >> 2) & 3, wb = r & 3;
  const ushort* qkv16 = (const ushort*)(ws + WS_QKV16);
  const ushort* src = qkv16 + (tensor ? QKV16_D : 0)
                    + (size_t)b*NCO*NN + (size_t)(96 + cb*16)*NN;
  ushort* dst = (ushort*)(ws + WS_SLABS) + (tensor ? OFF_VHD : OFF_VHU);
  int t = threadIdx.x;
  for (int k = 0; k < 8; k++) {
    int idx = t + k*256;                          // 2048 = 16c*32h*4(w8)
    int c = idx >> 7, h = (idx >> 2) & 31, w8 = idx & 3;
    uint4 v = *(const uint4*)(src + (size_t)c*NN + (size_t)(hb*32 + h)*NWID + wb*32 + w8*8);
    *(uint4*)&Br[c*1320 + h*40 + w8*8] = v;
  }
  __syncthreads();
  for (int k = 0; k < 2; k++) {
    int idx = t + k*256;                          // 512 = 32w*16c
    int w = idx >> 4, c = idx & 15;
    uint uu[16];
    #pragma unroll
    for (int hh = 0; hh < 16; hh++) {
      ushort a0 = Br[c*1320 + (2*hh)*40 + w];
      ushort a1 = Br[c*1320 + (2*hh+1)*40 + w];
      uu[hh] = (uint)a0 | ((uint)a1 << 16);
    }
    size_t o = ((size_t)(b*128 + wb*32 + w)*32 + cb*16 + c)*136 + hb*32;
    *(uint4*)(dst + o)      = make_uint4(uu[0],uu[1],uu[2],uu[3]);
    *(uint4*)(dst + o + 8)  = make_uint4(uu[4],uu[5],uu[6],uu[7]);
    *(uint4*)(dst + o + 16) = make_uint4(uu[8],uu[9],uu[10],uu[11]);
    *(uint4*)(dst + o + 24) = make_uint4(uu[12],uu[13],uu[14],uu[15]);
  }
}

// ---------------- MFMA spatial attention (AXIS 0 = h, 1 = w) ----------------
template<int AXIS>
__global__ __launch_bounds__(256) void attn_mfma(float* __restrict__ ws,
    const float* __restrict__ xu, const float* __restrict__ xd,
    float* __restrict__ out, const float* __restrict__ scale_p) {
  __shared__ __align__(16) ushort Qs[128*40];
  __shared__ __align__(16) ushort Ks[128*40];
  __shared__ __align__(16) ushort Vds[32*136];
  __shared__ __align__(16) ushort Vus[32*136];
  __shared__ __align__(16) ushort Pl[128*136];
  __shared__ float m1s[128], l1s[128];
  const int b = blockIdx.x >> 7, p2 = blockIdx.x & 127;
  const int t = threadIdx.x;
  const int wv = t >> 6, lid = t & 63, l15 = lid & 15, l4 = lid >> 4;
  const ushort* slab = (const ushort*)(ws + WS_SLABS);
  const ushort* qsrc  = slab + (AXIS ? OFF_QW : OFF_QH) + (size_t)(b*128 + p2)*5120;
  const ushort* ksrc  = slab + (AXIS ? OFF_KW : OFF_KH) + (size_t)(b*128 + p2)*5120;
  const ushort* vdsrc = slab + (AXIS ? OFF_VWD : OFF_VHD) + (size_t)(b*128 + p2)*4352;
  const ushort* vusrc = slab + (AXIS ? OFF_VWU : OFF_VHU) + (size_t)(b*128 + p2)*4352;
  for (int i = t; i < 2368; i += 256) {
    const uint4* s; uint4* d;
    if (i < 640)       { s = (const uint4*)qsrc + i;          d = (uint4*)Qs + i; }
    else if (i < 1280) { s = (const uint4*)ksrc + (i-640);    d = (uint4*)Ks + (i-640); }
    else if (i < 1824) { s = (const uint4*)vdsrc + (i-1280);  d = (uint4*)Vds + (i-1280); }
    else               { s = (const uint4*)vusrc + (i-1824);  d = (uint4*)Vus + (i-1824); }
    *d = *s;
  }
  const float sc = scale_p[0];
  const int cbas = AXIS ? 32 : 0;
  float ruv0 = ws[WS_RU + b*96 + cbas + l15];
  float ruv1 = ws[WS_RU + b*96 + cbas + 16 + l15];
  float rdv0 = ws[WS_RD + b*96 + cbas + l15];
  float rdv1 = ws[WS_RD + b*96 + cbas + 16 + l15];
  __syncthreads();

  f32x4 z4 = {0.f,0.f,0.f,0.f};
  f32x4 s1[2][8];
  // ---- S1[i][j] = sum_c Q[i][c] K[j][c], wave owns i-tiles {2wv,2wv+1} ----
  {
    bf16x8 bfr[8];
    #pragma unroll
    for (int tj = 0; tj < 8; tj++) bfr[tj] = ldfrag(&Ks[(tj*16 + l15)*40 + l4*8]);
    #pragma unroll
    for (int ti = 0; ti < 2; ti++) {
      bf16x8 a = ldfrag(&Qs[((2*wv+ti)*16 + l15)*40 + l4*8]);
      #pragma unroll
      for (int tj = 0; tj < 8; tj++)
        s1[ti][tj] = __builtin_amdgcn_mfma_f32_16x16x32_bf16(a, bfr[tj], z4, 0, 0, 0);
    }
  }
  // ---- row softmax over j; write P1 bf16 ----
  #pragma unroll
  for (int ti = 0; ti < 2; ti++) {
    #pragma unroll
    for (int r = 0; r < 4; r++) {
      float mx = -3.0e38f;
      #pragma unroll
      for (int tj = 0; tj < 8; tj++) { float v = s1[ti][tj][r]*sc; s1[ti][tj][r] = v; mx = fmaxf(mx, v); }
      mx = fmaxf(mx, __shfl_xor(mx, 1)); mx = fmaxf(mx, __shfl_xor(mx, 2));
      mx = fmaxf(mx, __shfl_xor(mx, 4)); mx = fmaxf(mx, __shfl_xor(mx, 8));
      float sm = 0.f;
      #pragma unroll
      for (int tj = 0; tj < 8; tj++) { float e = __expf(s1[ti][tj][r] - mx); s1[ti][tj][r] = e; sm += e; }
      sm += __shfl_xor(sm, 1); sm += __shfl_xor(sm, 2); sm += __shfl_xor(sm, 4); sm += __shfl_xor(sm, 8);
      int row = 32*wv + ti*16 + l4*4 + r;
      if (l15 == 0) { m1s[row] = mx; l1s[row] = sm; }
      float inv = __fdividef(1.f, sm);
      #pragma unroll
      for (int tj = 0; tj < 8; tj++) Pl[row*136 + tj*16 + l15] = f2bf(s1[ti][tj][r]*inv);
    }
  }
  __syncthreads();
  // ---- PV1: o1[i][c] = sum_j P1[i][j] Vd[c][j] ----
  f32x4 o1[2][2] = {{z4,z4},{z4,z4}};
  #pragma unroll
  for (int ks = 0; ks < 4; ks++) {
    bf16x8 bv0 = ldfrag(&Vds[l15*136 + ks*32 + l4*8]);
    bf16x8 bv1 = ldfrag(&Vds[(16 + l15)*136 + ks*32 + l4*8]);
    #pragma unroll
    for (int mt = 0; mt < 2; mt++) {
      bf16x8 a = ldfrag(&Pl[((2*wv+mt)*16 + l15)*136 + ks*32 + l4*8]);
      o1[mt][0] = __builtin_amdgcn_mfma_f32_16x16x32_bf16(a, bv0, o1[mt][0], 0, 0, 0);
      o1[mt][1] = __builtin_amdgcn_mfma_f32_16x16x32_bf16(a, bv1, o1[mt][1], 0, 0, 0);
    }
  }
  // ---- S2[j][i] = S1^T via mfma(K, Q) ----
  {
    bf16x8 bq[8];
    #pragma unroll
    for (int it = 0; it < 8; it++) bq[it] = ldfrag(&Qs[(it*16 + l15)*40 + l4*8]);
    #pragma unroll
    for (int tjt = 0; tjt < 2; tjt++) {
      bf16x8 a = ldfrag(&Ks[((2*wv+tjt)*16 + l15)*40 + l4*8]);
      #pragma unroll
      for (int it = 0; it < 8; it++)
        s1[tjt][it] = __builtin_amdgcn_mfma_f32_16x16x32_bf16(a, bq[it], z4, 0, 0, 0);
    }
  }
  // ---- pass-2 softmax ----
  if (AXIS == 1) {
    #pragma unroll
    for (int tjt = 0; tjt < 2; tjt++) {
      #pragma unroll
      for (int r = 0; r < 4; r++) {
        float mx = -3.0e38f;
        #pragma unroll
        for (int it = 0; it < 8; it++) { float v = s1[tjt][it][r]*sc; s1[tjt][it][r] = v; mx = fmaxf(mx, v); }
        mx = fmaxf(mx, __shfl_xor(mx, 1)); mx = fmaxf(mx, __shfl_xor(mx, 2));
        mx = fmaxf(mx, __shfl_xor(mx, 4)); mx = fmaxf(mx, __shfl_xor(mx, 8));
        float sm = 0.f;
        #pragma unroll
        for (int it = 0; it < 8; it++) { float e = __expf(s1[tjt][it][r] - mx); s1[tjt][it][r] = e; sm += e; }
        sm += __shfl_xor(sm, 1); sm += __shfl_xor(sm, 2); sm += __shfl_xor(sm, 4); sm += __shfl_xor(sm, 8);
        float inv = __fdividef(1.f, sm);
        #pragma unroll
        for (int it = 0; it < 8; it++) s1[tjt][it][r] *= inv;
      }
    }
  } else {
    float mi[8], li[8];
    #pragma unroll
    for (int it = 0; it < 8; it++) {
      mi[it] = m1s[it*16 + l15];
      li[it] = __fdividef(1.f, l1s[it*16 + l15]);
    }
    #pragma unroll
    for (int tjt = 0; tjt < 2; tjt++)
      #pragma unroll
      for (int it = 0; it < 8; it++)
        #pragma unroll
        for (int r = 0; r < 4; r++)
          s1[tjt][it][r] = __expf(s1[tjt][it][r]*sc - mi[it]) * li[it];
  }
  __syncthreads();   // all PV1 reads of Pl done
  #pragma unroll
  for (int tjt = 0; tjt < 2; tjt++)
    #pragma unroll
    for (int r = 0; r < 4; r++) {
      int row = 32*wv + tjt*16 + l4*4 + r;
      #pragma unroll
      for (int it = 0; it < 8; it++) Pl[row*136 + it*16 + l15] = f2bf(s1[tjt][it][r]);
    }
  __syncthreads();
  // ---- PV2: o2[j][c] = sum_i P2[j][i] Vu[c][i] ----
  f32x4 o2[2][2] = {{z4,z4},{z4,z4}};
  #pragma unroll
  for (int ks = 0; ks < 4; ks++) {
    bf16x8 bv0 = ldfrag(&Vus[l15*136 + ks*32 + l4*8]);
    bf16x8 bv1 = ldfrag(&Vus[(16 + l15)*136 + ks*32 + l4*8]);
    #pragma unroll
    for (int mt = 0; mt < 2; mt++) {
      bf16x8 a = ldfrag(&Pl[((2*wv+mt)*16 + l15)*136 + ks*32 + l4*8]);
      o2[mt][0] = __builtin_amdgcn_mfma_f32_16x16x32_bf16(a, bv0, o2[mt][0], 0, 0, 0);
      o2[mt][1] = __builtin_amdgcn_mfma_f32_16x16x32_bf16(a, bv1, o2[mt][1], 0, 0, 0);
    }
  }
  __syncthreads();   // PV2 reads done; reuse Pl as fp32 stage [32][132]
  float* St = (float*)Pl;
  #pragma unroll
  for (int mt = 0; mt < 2; mt++)
    #pragma unroll
    for (int nt = 0; nt < 2; nt++) {
      float ru = nt ? ruv1 : ruv0;
      float rd = nt ? rdv1 : rdv0;
      float4 vv;
      vv.x = o1[mt][nt][0]*ru + o2[mt][nt][0]*rd;
      vv.y = o1[mt][nt][1]*ru + o2[mt][nt][1]*rd;
      vv.z = o1[mt][nt][2]*ru + o2[mt][nt][2]*rd;
      vv.w = o1[mt][nt][3]*ru + o2[mt][nt][3]*rd;
      *(float4*)&St[(nt*16 + l15)*132 + (2*wv+mt)*16 + l4*4] = vv;
    }
  __syncthreads();
  if (AXIS == 1) {
    for (int k = 0; k < 4; k++) {
      int idx = t + k*256;
      int c = idx >> 5, p4 = idx & 31;
      float4 v = *(const float4*)&St[c*132 + p4*4];
      float ca = ws[WS_CADD + b*96 + 32 + c];
      size_t off = ((size_t)(b*NC + 32 + c)*NH + p2)*NWID + p4*4;
      float4 a = *(const float4*)(xu + off);
      float4 dd = *(const float4*)(xd + off);
      v.x += ca + a.x + dd.x; v.y += ca + a.y + dd.y;
      v.z += ca + a.z + dd.z; v.w += ca + a.w + dd.w;
      *(float4*)(out + off) = v;
    }
  } else {
    float* oh = ws + WS_OH;
    for (int k = 0; k < 4; k++) {
      int idx = t + k*256;
      int c = idx >> 5, p4 = idx & 31;
      float4 v = *(const float4*)&St[c*132 + p4*4];
      *(float4*)(oh + ((size_t)(b*128 + p2)*32 + c)*128 + p4*4) = v;
    }
  }
}

// ---------------- merge h-attn staging into final out (ch 0..31) ----------------
__global__ __launch_bounds__(256) void merge_h(float* __restrict__ ws,
    const float* __restrict__ xu, const float* __restrict__ xd,
    float* __restrict__ out) {
  __shared__ float T[32][33];
  int bid = blockIdx.x;                 // 8b*32c*4ht*4wt = 4096
  int b = bid >> 9, c = (bid >> 4) & 31, ht = (bid >> 2) & 3, wt = bid & 3;
  int t = threadIdx.x;
  const float* oh = ws + WS_OH;
  {
    int w = t >> 3, h4 = t & 7;
    float4 v = *(const float4*)(oh + ((size_t)(b*128 + wt*32 + w)*32 + c)*128 + ht*32 + h4*4);
    T[w][h4*4+0] = v.x; T[w][h4*4+1] = v.y; T[w][h4*4+2] = v.z; T[w][h4*4+3] = v.w;
  }
  __syncthreads();
  {
    int h = t >> 3, w4 = t & 7;
    float ca = ws[WS_CADD + b*96 + c];
    size_t off = ((size_t)(b*NC + c)*NH + ht*32 + h)*NWID + wt*32 + w4*4;
    float4 a = *(const float4*)(xu + off);
    float4 d = *(const float4*)(xd + off);
    float4 v;
    v.x = T[w4*4+0][h] + ca + a.x + d.x;
    v.y = T[w4*4+1][h] + ca + a.y + d.y;
    v.z = T[w4*4+2][h] + ca + a.z + d.z;
    v.w = T[w4*4+3][h] + ca + a.w + d.w;
    *(float4*)(out + off) = v;
  }
}

// ---------------- channel attention: score accumulation (bf16 in) ----------------
__global__ __launch_bounds__(256) void attn_c1(float* __restrict__ ws) {
  __shared__ float qs[32][260], ks[32][260];
  int b = blockIdx.x >> 6, chunk = blockIdx.x & 63;
  int n0 = chunk * 256;
  int t = threadIdx.x;
  const ushort* qkv16 = (const ushort*)(ws + WS_QKV16);
  const ushort* qp = qkv16 + ((size_t)b*NCO + 64)*NN + n0;
  const ushort* kp = qkv16 + QKV16_D + ((size_t)b*NCO + 64)*NN + n0;
  for (int r = 0; r < 4; r++) {
    int idx = t + r*256;
    int c = idx >> 5, n8 = idx & 31;
    uint4 v = *(const uint4*)(qp + (size_t)c*NN + n8*8);
    uint4 w = *(const uint4*)(kp + (size_t)c*NN + n8*8);
    float* q = &qs[c][n8*8];
    float* kk = &ks[c][n8*8];
    q[0] = bf2f((ushort)(v.x & 0xffff)); q[1] = bf2f((ushort)(v.x >> 16));
    q[2] = bf2f((ushort)(v.y & 0xffff)); q[3] = bf2f((ushort)(v.y >> 16));
    q[4] = bf2f((ushort)(v.z & 0xffff)); q[5] = bf2f((ushort)(v.z >> 16));
    q[6] = bf2f((ushort)(v.w & 0xffff)); q[7] = bf2f((ushort)(v.w >> 16));
    kk[0] = bf2f((ushort)(w.x & 0xffff)); kk[1] = bf2f((ushort)(w.x >> 16));
    kk[2] = bf2f((ushort)(w.y & 0xffff)); kk[3] = bf2f((ushort)(w.y >> 16));
    kk[4] = bf2f((ushort)(w.z & 0xffff)); kk[5] = bf2f((ushort)(w.z >> 16));
    kk[6] = bf2f((ushort)(w.w & 0xffff)); kk[7] = bf2f((ushort)(w.w >> 16));
  }
  __syncthreads();
  int d = t & 31, cbq = t >> 5;
  float a[4] = {0.f,0.f,0.f,0.f};
  for (int n4 = 0; n4 < 64; n4++) {
    float4 kv = *(const float4*)&ks[d][n4*4];
    #pragma unroll
    for (int r = 0; r < 4; r++) {
      float4 qv = *(const float4*)&qs[cbq + 8*r][n4*4];
      a[r] += qv.x*kv.x + qv.y*kv.y + qv.z*kv.z + qv.w*kv.w;
    }
  }
  #pragma unroll
  for (int r = 0; r < 4; r++)
    atomicAdd(&ws[WS_SC + b*1024 + (cbq + 8*r)*32 + d], a[r]);
}

// ---------------- channel attention: softmax ----------------
__global__ void attn_c2(float* __restrict__ ws, const float* __restrict__ scale_p) {
  int b = blockIdx.x, c = threadIdx.x;
  if (c >= 32) return;
  float sc = scale_p[0];
  float row[32];
  float m = -3.0e38f;
  for (int d = 0; d < 32; d++) { row[d] = ws[WS_SC + b*1024 + c*32 + d] * sc; m = fmaxf(m, row[d]); }
  float s = 0.f;
  for (int d = 0; d < 32; d++) { row[d] = __expf(row[d] - m); s += row[d]; }
  float inv = 1.f / s;
  for (int d = 0; d < 32; d++) ws[WS_AC + b*1024 + c*32 + d] = row[d]*inv;
}

// ---------------- channel attention: apply + epilogue (ch 64..95) ----------------
__global__ __launch_bounds__(256) void attn_c3(float* __restrict__ ws,
    const float* __restrict__ xu, const float* __restrict__ xd,
    float* __restrict__ out) {
  __shared__ float AsT[32][36];
  __shared__ float ruL[32], rdL[32], caL[32];
  int b = blockIdx.x >> 6, chunk = blockIdx.x & 63;
  int t = threadIdx.x;
  for (int r = 0; r < 4; r++) {
    int idx = t + r*256;
    int c = idx >> 5, d = idx & 31;
    AsT[d][c] = ws[WS_AC + b*1024 + idx];
  }
  if (t < 32) {
    ruL[t] = ws[WS_RU + b*96 + 64 + t];
    rdL[t] = ws[WS_RD + b*96 + 64 + t];
    caL[t] = ws[WS_CADD + b*96 + 64 + t];
  }
  __syncthreads();
  int n = chunk*256 + t;
  const ushort* qkv16 = (const ushort*)(ws + WS_QKV16);
  const ushort* vdp = qkv16 + QKV16_D + ((size_t)b*NCO + 160)*NN + n;
  const ushort* vup = qkv16 + ((size_t)b*NCO + 160)*NN + n;
  float acc1[32], acc2[32];
  #pragma unroll
  for (int c2 = 0; c2 < 32; c2++) { acc1[c2]=0.f; acc2[c2]=0.f; }
  for (int d = 0; d < 32; d++) {
    float vd = bf2f(vdp[(size_t)d*NN]);
    float vu = bf2f(vup[(size_t)d*NN]);
    #pragma unroll
    for (int c4 = 0; c4 < 8; c4++) {
      float4 av = *(const float4*)&AsT[d][c4*4];
      acc1[c4*4+0] += av.x*vd; acc2[c4*4+0] += av.x*vu;
      acc1[c4*4+1] += av.y*vd; acc2[c4*4+1] += av.y*vu;
      acc1[c4*4+2] += av.z*vd; acc2[c4*4+2] += av.z*vu;
      acc1[c4*4+3] += av.w*vd; acc2[c4*4+3] += av.w*vu;
    }
  }
  size_t base = ((size_t)(b*NC) + 64)*NN + n;
  #pragma unroll
  for (int c2 = 0; c2 < 32; c2++) {
    size_t off = base + (size_t)c2*NN;
    out[off] = acc1[c2]*ruL[c2] + acc2[c2]*rdL[c2] + caL[c2] + xu[off] + xd[off];
  }
}

extern "C" void kernel_launch(void* const* d_in, const int* in_sizes, int n_in,
                              void* d_out, int out_size, void* d_ws, size_t ws_size,
                              hipStream_t stream) {
  (void)in_sizes; (void)n_in; (void)out_size; (void)ws_size;
  const float* xu   = (const float*)d_in[0];
  const float* xd   = (const float*)d_in[1];
  const float* nwu  = (const float*)d_in[2];
  const float* nbu  = (const float*)d_in[3];
  const float* m1wu = (const float*)d_in[4];
  const float* m1bu = (const float*)d_in[5];
  const float* m2wu = (const float*)d_in[6];
  const float* m2bu = (const float*)d_in[7];
  const float* nwd  = (const float*)d_in[8];
  const float* nbd  = (const float*)d_in[9];
  const float* m1wd = (const float*)d_in[10];
  const float* m1bd = (const float*)d_in[11];
  const float* m2wd = (const float*)d_in[12];
  const float* m2bd = (const float*)d_in[13];
  const float* Wqu  = (const float*)d_in[14];
  const float* bqu  = (const float*)d_in[15];
  const float* Wqd  = (const float*)d_in[16];
  const float* bqd  = (const float*)d_in[17];
  const float* sch  = (const float*)d_in[18];
  const float* scw  = (const float*)d_in[19];
  const float* scc  = (const float*)d_in[20];
  float* ws  = (float*)d_ws;
  float* out = (float*)d_out;

  hipMemsetAsync(d_ws, 0, 8224*sizeof(float), stream);
  reduce_stats<<<1024, 256, 0, stream>>>(xu, xd, ws);
  compute_params<<<1, 256, 0, stream>>>(ws, nwu, nbu, m1wu, m1bu, m2wu, m2bu,
                                        nwd, nbd, m1wd, m1bd, m2wd, m2bd,
                                        Wqu, bqu, Wqd, bqd);
  compute_wprime<<<1248, 256, 0, stream>>>(ws, Wqu, Wqd);
  qkv_gemm<<<2048, 256, 0, stream>>>(ws, xu, xd);
  qkv_prep<<<512, 256, 0, stream>>>(ws);
  attn_mfma<0><<<1024, 256, 0, stream>>>(ws, xu, xd, out, sch);
  attn_mfma<1><<<1024, 256, 0, stream>>>(ws, xu, xd, out, scw);
  merge_h<<<4096, 256, 0, stream>>>(ws, xu, xd, out);
  attn_c1<<<512, 256, 0, stream>>>(ws);
  attn_c2<<<8, 64, 0, stream>>>(ws, scc);
  attn_c3<<<512, 256, 0, stream>>>(ws, xu, xd, out);
}